// Round 14
// baseline (376.431 us; speedup 1.0000x reference)
//
#include <hip/hip_runtime.h>

// GCN 2-layer, deterministic sort + LDS aggregation (gfx950).
// History: global fp32 atomics EA-bound -> eliminated (r5); cursor scatter
// raced -> deterministic partition sort (r9); LDS-reorder scatter + fusions
// (r10); SPLIT=4 (r11). r12 lesson: per-element `if` guards around the staged
// gathers forced load->wait->branch chains (VGPR=16 proves <=4 in flight);
// the 8-deep ILP never reached the ISA. Round-13: branchless batch -- clamped
// indices + 0/1 mask, unconditional loads, masked LDS-atomic contribution
// (+0.0 exact). Little's law: ~4900 waves x 8 outstanding should cover the
// ~125ns L2 gather latency.
// (r13 submission never ran -- infra push failure; identical resubmit.)

typedef unsigned int u32;
typedef unsigned short u16;

#define BUCKET_BITS 9
#define BUCKET_SIZE (1 << BUCKET_BITS)   // 512 nodes per bucket
#define MAX_NBUCK 512                    // supports N <= 262144
#define PCHUNK 8192                      // edges per partition chunk
#define STHREADS 512
#define MAX_NB 1024                      // supports E <= 8.4M
#define SPLIT 4                          // split-blocks per bucket edge pass
#define BATCH 8                          // staged edges per thread per batch

// K1: per-chunk bucket histogram -> part[c*nbuck + j]  (no global atomics)
__global__ void part_hist_kernel(const int* __restrict__ dst, u32* __restrict__ part,
                                 int E, int nbuck) {
    __shared__ u32 h[MAX_NBUCK];
    int t = threadIdx.x, c = blockIdx.x;
    h[t] = 0;
    __syncthreads();
    int start = c * PCHUNK, end = min(start + PCHUNK, E);
    for (int i = start + t; i < end; i += STHREADS)
        atomicAdd(&h[((u32)dst[i]) >> BUCKET_BITS], 1u);
    __syncthreads();
    for (int j = t; j < nbuck; j += STHREADS)
        part[(size_t)c * nbuck + j] = h[j];
}

// K2: per-bucket exclusive prefix across chunks (in place); totals -> cnt[j]
__global__ void colscan_kernel(u32* __restrict__ part, u32* __restrict__ cnt,
                               int NB, int nbuck) {
    __shared__ u32 s[MAX_NB];
    int t = threadIdx.x, j = blockIdx.x;  // 1024 threads, j < nbuck
    u32 v = (t < NB) ? part[(size_t)t * nbuck + j] : 0u;
    s[t] = v;
    for (int o = 1; o < MAX_NB; o <<= 1) {
        __syncthreads();
        u32 u = (t >= o) ? s[t - o] : 0u;
        __syncthreads();
        s[t] += u;
    }
    __syncthreads();
    if (t < NB) part[(size_t)t * nbuck + j] = s[t] - v;  // exclusive prefix
    if (t == MAX_NB - 1) cnt[j] = s[MAX_NB - 1];         // bucket total
}

// K3: exclusive scan of bucket totals -> offsets[0..nbuck]
__global__ void offsets_kernel(const u32* __restrict__ cnt, u32* __restrict__ offsets,
                               int nbuck) {
    __shared__ u32 s[MAX_NBUCK];
    int t = threadIdx.x;  // 512
    u32 v = (t < nbuck) ? cnt[t] : 0u;
    s[t] = v;
    for (int o = 1; o < MAX_NBUCK; o <<= 1) {
        __syncthreads();
        u32 u = (t >= o) ? s[t - o] : 0u;
        __syncthreads();
        s[t] += u;
    }
    __syncthreads();
    if (t < nbuck) offsets[t + 1] = s[t];
    if (t == 0) offsets[0] = 0;
}

// K4: LDS-reorder scatter, precomputed bases (replay-proven in r10)
__global__ void __launch_bounds__(STHREADS)
scatter_kernel(const int* __restrict__ src, const int* __restrict__ dst,
               const u32* __restrict__ part, const u32* __restrict__ offsets,
               u32* __restrict__ sorted, int E, int nbuck) {
    __shared__ u32 pk[PCHUNK];
    __shared__ u16 bk[PCHUNK];
    __shared__ u32 hist[MAX_NBUCK];
    __shared__ u32 scr[MAX_NBUCK];
    __shared__ u32 dadj[MAX_NBUCK];
    int t = threadIdx.x, c = blockIdx.x;
    int start = c * PCHUNK, end = min(start + PCHUNK, E);
    int cntE = end - start;

    hist[t] = 0;
    __syncthreads();
    for (int i = start + t; i < end; i += STHREADS)
        atomicAdd(&hist[((u32)dst[i]) >> BUCKET_BITS], 1u);
    __syncthreads();
    u32 v = hist[t];
    scr[t] = v;
    for (int o = 1; o < MAX_NBUCK; o <<= 1) {
        __syncthreads();
        u32 u = (t >= o) ? scr[t - o] : 0u;
        __syncthreads();
        scr[t] += u;
    }
    __syncthreads();
    u32 lb = scr[t] - v;
    hist[t] = lb;
    if (t < nbuck)
        dadj[t] = offsets[t] + part[(size_t)c * nbuck + t] - lb;
    scr[t] = 0;
    __syncthreads();
    for (int i = start + t; i < end; i += STHREADS) {
        u32 d = (u32)dst[i];
        u32 b = d >> BUCKET_BITS;
        u32 p = hist[b] + atomicAdd(&scr[b], 1u);
        pk[p] = ((u32)src[i] << BUCKET_BITS) | (d & (BUCKET_SIZE - 1));
        bk[p] = (u16)b;
    }
    __syncthreads();
    for (int i = t; i < cntE; i += STHREADS)
        sorted[dadj[bk[i]] + i] = pk[i];
}

// K5: split degree count -> pdeg[block][t]  (branchless batched)
__global__ void __launch_bounds__(BUCKET_SIZE)
deg_part_kernel(const u32* __restrict__ sorted, const u32* __restrict__ offsets,
                u32* __restrict__ pdeg) {
    __shared__ u32 cnt_s[BUCKET_SIZE];
    int t = threadIdx.x;
    int b = blockIdx.x / SPLIT, s = blockIdx.x % SPLIT;
    cnt_s[t] = 0;
    __syncthreads();
    u32 e0 = offsets[b], len = offsets[b + 1] - e0;
    u32 lo = e0 + (len * s) / SPLIT, hi = e0 + (len * (s + 1)) / SPLIT;
    if (lo >= hi) { __syncthreads();
                    pdeg[(size_t)blockIdx.x * BUCKET_SIZE + t] = 0; return; }
    for (u32 base = lo; base < hi; base += BATCH * BUCKET_SIZE) {
        u32 e[BATCH], m[BATCH];
#pragma unroll
        for (int k = 0; k < BATCH; ++k) {
            u32 i = base + (u32)k * BUCKET_SIZE + t;
            u32 ok = (i < hi) ? 1u : 0u;
            e[k] = sorted[ok ? i : (hi - 1)];   // unconditional load
            m[k] = ok;
        }
#pragma unroll
        for (int k = 0; k < BATCH; ++k)
            atomicAdd(&cnt_s[e[k] & (BUCKET_SIZE - 1)], m[k]);  // +0 for pads
    }
    __syncthreads();
    pdeg[(size_t)blockIdx.x * BUCKET_SIZE + t] = cnt_s[t];
}

// K6: combine degree partials; dinv = rsqrt(deg+1); y = dinv * x
__global__ void dinv_y_kernel(const u32* __restrict__ pdeg, const float2* __restrict__ x,
                              float* __restrict__ dinv, float2* __restrict__ y, int N) {
    int b = blockIdx.x, t = threadIdx.x;
    int node = (b << BUCKET_BITS) + t;
    if (node >= N) return;
    u32 d = 0;
#pragma unroll
    for (int s = 0; s < SPLIT; ++s)
        d += pdeg[((size_t)(b * SPLIT + s)) * BUCKET_SIZE + t];
    float di = rsqrtf((float)d + 1.0f);  // +1 self-loop, always > 0
    dinv[node] = di;
    float2 xv = x[node];
    y[node] = make_float2(di * xv.x, di * xv.y);
}

// K7 (used twice): split aggregation, branchless 8-deep staging.
// All loads unconditional (clamped index); contribution masked by 0/1.
__global__ void __launch_bounds__(BUCKET_SIZE)
aggp_kernel(const u32* __restrict__ sorted, const u32* __restrict__ offsets,
            const float2* __restrict__ feat, float2* __restrict__ pagg) {
    __shared__ float accx[BUCKET_SIZE];
    __shared__ float accy[BUCKET_SIZE];
    int t = threadIdx.x;
    int b = blockIdx.x / SPLIT, s = blockIdx.x % SPLIT;
    accx[t] = 0.f;
    accy[t] = 0.f;
    __syncthreads();
    u32 e0 = offsets[b], len = offsets[b + 1] - e0;
    u32 lo = e0 + (len * s) / SPLIT, hi = e0 + (len * (s + 1)) / SPLIT;
    if (lo >= hi) { __syncthreads();
                    pagg[(size_t)blockIdx.x * BUCKET_SIZE + t] = make_float2(0.f, 0.f);
                    return; }
    for (u32 base = lo; base < hi; base += BATCH * BUCKET_SIZE) {
        u32 e[BATCH];
        float m[BATCH];
#pragma unroll
        for (int k = 0; k < BATCH; ++k) {
            u32 i = base + (u32)k * BUCKET_SIZE + t;
            u32 ok = (i < hi) ? 1u : 0u;
            e[k] = sorted[ok ? i : (hi - 1)];   // unconditional coalesced load
            m[k] = (float)ok;
        }
        float2 v[BATCH];
#pragma unroll
        for (int k = 0; k < BATCH; ++k)
            v[k] = feat[e[k] >> BUCKET_BITS];   // unconditional gather: 8 in flight
#pragma unroll
        for (int k = 0; k < BATCH; ++k) {
            u32 ld = e[k] & (BUCKET_SIZE - 1);
            atomicAdd(&accx[ld], v[k].x * m[k]);  // masked: pads add exact 0.0
            atomicAdd(&accy[ld], v[k].y * m[k]);
        }
    }
    __syncthreads();
    pagg[(size_t)blockIdx.x * BUCKET_SIZE + t] = make_float2(accx[t], accy[t]);
}

// K8: combine layer-1 partials + self-loop, then fused 2->16->2 MLP
__global__ void mlp_combine_kernel(const float2* __restrict__ pagg, const float2* __restrict__ y,
                                   const float* __restrict__ dinv,
                                   const float* __restrict__ W1, const float* __restrict__ b1,
                                   const float* __restrict__ W2,
                                   float2* __restrict__ gp, int N) {
    int b = blockIdx.x, t = threadIdx.x;
    int node = (b << BUCKET_BITS) + t;
    if (node >= N) return;
    float sx = 0.f, sy = 0.f;
#pragma unroll
    for (int s = 0; s < SPLIT; ++s) {
        float2 p = pagg[((size_t)(b * SPLIT + s)) * BUCKET_SIZE + t];
        sx += p.x; sy += p.y;
    }
    float di = dinv[node];
    float2 yv = y[node];
    float ax = di * (sx + yv.x);
    float ay = di * (sy + yv.y);
    float g0 = 0.f, g1 = 0.f;
#pragma unroll
    for (int j = 0; j < 16; ++j) {
        float h = fmaf(ax, W1[j], fmaf(ay, W1[16 + j], b1[j]));
        h = fmaxf(h, 0.f);
        g0 = fmaf(h, W2[2 * j], g0);
        g1 = fmaf(h, W2[2 * j + 1], g1);
    }
    gp[node] = make_float2(di * g0, di * g1);
}

// K9: combine layer-2 partials + self-loop + bias -> out
__global__ void final_combine_kernel(const float2* __restrict__ pagg, const float2* __restrict__ gp,
                                     const float* __restrict__ dinv, const float* __restrict__ b2,
                                     float2* __restrict__ out, int N) {
    int b = blockIdx.x, t = threadIdx.x;
    int node = (b << BUCKET_BITS) + t;
    if (node >= N) return;
    float sx = 0.f, sy = 0.f;
#pragma unroll
    for (int s = 0; s < SPLIT; ++s) {
        float2 p = pagg[((size_t)(b * SPLIT + s)) * BUCKET_SIZE + t];
        sx += p.x; sy += p.y;
    }
    float di = dinv[node];
    float2 gv = gp[node];
    out[node] = make_float2(fmaf(di, sx + gv.x, b2[0]),
                            fmaf(di, sy + gv.y, b2[1]));
}

extern "C" void kernel_launch(void* const* d_in, const int* in_sizes, int n_in,
                              void* d_out, int out_size, void* d_ws, size_t ws_size,
                              hipStream_t stream) {
    const float2* x  = (const float2*)d_in[0];
    const int*    ei = (const int*)d_in[1];   // [2, E]: src row then dst row
    const float*  W1 = (const float*)d_in[2];
    const float*  b1 = (const float*)d_in[3];
    const float*  W2 = (const float*)d_in[4];
    const float*  b2 = (const float*)d_in[5];

    const int N = in_sizes[0] / 2;
    const int E = in_sizes[1] / 2;
    const int* src = ei;
    const int* dst = ei + E;
    const int nbuck = (N + BUCKET_SIZE - 1) >> BUCKET_BITS;   // 391
    const int NB    = (E + PCHUNK - 1) / PCHUNK;              // 782 (<= 1024)

    // Workspace (lifetime-ordered aliases, all pure functions of inputs):
    //   part  (NB*nbuck u32, ~1.2MB) aliases y  : dead before deg_y writes y
    //   pdeg  (nbuck*SPLIT*512 u32)  aliases pagg: dead before aggp writes pagg
    //   pagg reused by both agg passes (combine1 reads before agg2 rewrites)
    u32* sorted   = (u32*)d_ws;                               // E
    float* dinv   = (float*)(sorted + E);                     // N
    float* y      = dinv + N;                                 // 2N
    float* gp     = y + 2 * (size_t)N;                        // 2N
    float2* pagg  = (float2*)(gp + 2 * (size_t)N);            // nbuck*SPLIT*512
    u32* pdeg     = (u32*)pagg;                               // alias (half size)
    u32* cnt      = (u32*)(pagg + (size_t)nbuck * SPLIT * BUCKET_SIZE); // 512
    u32* offsets  = cnt + MAX_NBUCK;                          // nbuck+1
    u32* part     = (u32*)y;                                  // alias
    float2* out   = (float2*)d_out;

    part_hist_kernel  <<<NB, STHREADS, 0, stream>>>(dst, part, E, nbuck);
    colscan_kernel    <<<nbuck, MAX_NB, 0, stream>>>(part, cnt, NB, nbuck);
    offsets_kernel    <<<1, MAX_NBUCK, 0, stream>>>(cnt, offsets, nbuck);
    scatter_kernel    <<<NB, STHREADS, 0, stream>>>(src, dst, part, offsets, sorted, E, nbuck);
    deg_part_kernel   <<<nbuck * SPLIT, BUCKET_SIZE, 0, stream>>>(sorted, offsets, pdeg);
    dinv_y_kernel     <<<nbuck, BUCKET_SIZE, 0, stream>>>(pdeg, x, dinv, (float2*)y, N);
    aggp_kernel       <<<nbuck * SPLIT, BUCKET_SIZE, 0, stream>>>(sorted, offsets,
                                                                  (const float2*)y, pagg);
    mlp_combine_kernel<<<nbuck, BUCKET_SIZE, 0, stream>>>(pagg, (const float2*)y, dinv,
                                                          W1, b1, W2, (float2*)gp, N);
    aggp_kernel       <<<nbuck * SPLIT, BUCKET_SIZE, 0, stream>>>(sorted, offsets,
                                                                  (const float2*)gp, pagg);
    final_combine_kernel<<<nbuck, BUCKET_SIZE, 0, stream>>>(pagg, (const float2*)gp, dinv,
                                                            b2, out, N);
}

// Round 15
// 206.643 us; speedup vs baseline: 1.8217x; 1.8217x over previous
//
#include <hip/hip_runtime.h>

// GCN 2-layer, fully-deterministic two-level sort + register aggregation.
// History: global fp32 atomics EA-bound (r1-2) -> bucket sort + LDS atomics
// (r5-14). r11-r14 showed the LDS-atomic agg pass is stuck at ~78us: ~5-7
// CU-cycles/edge (divergent gather issue + 2 LDS atomics), and compiler
// defeats per-thread ILP staging (VGPR 4/16/20 across attempts).
// Round-15: second-level counting sort by local dst (per-bucket, in LDS) ->
// edges fully grouped by destination node. Aggregation = thread-per-node
// register accumulation: NO LDS, NO atomics, 4-wide strip-mined gathers.
// sort2 also emits node offsets, degree -> dinv, y (absorbs deg/dinv_y and
// removes all partial/combine machinery).

typedef unsigned int u32;
typedef unsigned short u16;

#define BUCKET_BITS 9
#define BUCKET_SIZE (1 << BUCKET_BITS)   // 512 nodes per bucket
#define MAX_NBUCK 512                    // supports N <= 262144
#define PCHUNK 8192                      // edges per partition chunk
#define STHREADS 512
#define MAX_NB 1024                      // supports E <= 8.4M
#define LDSCAP 17408                     // max edges staged per bucket (68KB)

// K1: per-chunk bucket histogram -> part[c*nbuck + j]  (no global atomics)
__global__ void part_hist_kernel(const int* __restrict__ dst, u32* __restrict__ part,
                                 int E, int nbuck) {
    __shared__ u32 h[MAX_NBUCK];
    int t = threadIdx.x, c = blockIdx.x;
    h[t] = 0;
    __syncthreads();
    int start = c * PCHUNK, end = min(start + PCHUNK, E);
    for (int i = start + t; i < end; i += STHREADS)
        atomicAdd(&h[((u32)dst[i]) >> BUCKET_BITS], 1u);
    __syncthreads();
    for (int j = t; j < nbuck; j += STHREADS)
        part[(size_t)c * nbuck + j] = h[j];
}

// K2: per-bucket exclusive prefix across chunks (in place); totals -> cnt[j]
__global__ void colscan_kernel(u32* __restrict__ part, u32* __restrict__ cnt,
                               int NB, int nbuck) {
    __shared__ u32 s[MAX_NB];
    int t = threadIdx.x, j = blockIdx.x;  // 1024 threads, j < nbuck
    u32 v = (t < NB) ? part[(size_t)t * nbuck + j] : 0u;
    s[t] = v;
    for (int o = 1; o < MAX_NB; o <<= 1) {
        __syncthreads();
        u32 u = (t >= o) ? s[t - o] : 0u;
        __syncthreads();
        s[t] += u;
    }
    __syncthreads();
    if (t < NB) part[(size_t)t * nbuck + j] = s[t] - v;  // exclusive prefix
    if (t == MAX_NB - 1) cnt[j] = s[MAX_NB - 1];         // bucket total
}

// K3: exclusive scan of bucket totals -> offsets[0..nbuck]
__global__ void offsets_kernel(const u32* __restrict__ cnt, u32* __restrict__ offsets,
                               int nbuck) {
    __shared__ u32 s[MAX_NBUCK];
    int t = threadIdx.x;  // 512
    u32 v = (t < nbuck) ? cnt[t] : 0u;
    s[t] = v;
    for (int o = 1; o < MAX_NBUCK; o <<= 1) {
        __syncthreads();
        u32 u = (t >= o) ? s[t - o] : 0u;
        __syncthreads();
        s[t] += u;
    }
    __syncthreads();
    if (t < nbuck) offsets[t + 1] = s[t];
    if (t == 0) offsets[0] = 0;
}

// K4: LDS-reorder scatter, precomputed bases (replay-proven r10-r14)
__global__ void __launch_bounds__(STHREADS)
scatter_kernel(const int* __restrict__ src, const int* __restrict__ dst,
               const u32* __restrict__ part, const u32* __restrict__ offsets,
               u32* __restrict__ sorted, int E, int nbuck) {
    __shared__ u32 pk[PCHUNK];
    __shared__ u16 bk[PCHUNK];
    __shared__ u32 hist[MAX_NBUCK];
    __shared__ u32 scr[MAX_NBUCK];
    __shared__ u32 dadj[MAX_NBUCK];
    int t = threadIdx.x, c = blockIdx.x;
    int start = c * PCHUNK, end = min(start + PCHUNK, E);
    int cntE = end - start;

    hist[t] = 0;
    __syncthreads();
    for (int i = start + t; i < end; i += STHREADS)
        atomicAdd(&hist[((u32)dst[i]) >> BUCKET_BITS], 1u);
    __syncthreads();
    u32 v = hist[t];
    scr[t] = v;
    for (int o = 1; o < MAX_NBUCK; o <<= 1) {
        __syncthreads();
        u32 u = (t >= o) ? scr[t - o] : 0u;
        __syncthreads();
        scr[t] += u;
    }
    __syncthreads();
    u32 lb = scr[t] - v;
    hist[t] = lb;
    if (t < nbuck)
        dadj[t] = offsets[t] + part[(size_t)c * nbuck + t] - lb;
    scr[t] = 0;
    __syncthreads();
    for (int i = start + t; i < end; i += STHREADS) {
        u32 d = (u32)dst[i];
        u32 b = d >> BUCKET_BITS;
        u32 p = hist[b] + atomicAdd(&scr[b], 1u);
        pk[p] = ((u32)src[i] << BUCKET_BITS) | (d & (BUCKET_SIZE - 1));
        bk[p] = (u16)b;
    }
    __syncthreads();
    for (int i = t; i < cntE; i += STHREADS)
        sorted[dadj[bk[i]] + i] = pk[i];
}

// K5: per-bucket second-level counting sort by local dst, IN PLACE (bucket
// staged in LDS, then `sorted` region overwritten with src-only, node-run
// order). Also emits node offsets, degree -> dinv, y = dinv*x.
__global__ void __launch_bounds__(STHREADS)
sort2_kernel(u32* __restrict__ sorted /* in: packed; out: ssrc */,
             const u32* __restrict__ offsets, const float2* __restrict__ x,
             u32* __restrict__ noff, float* __restrict__ dinv,
             float2* __restrict__ y, int N) {
    __shared__ u32 buf[LDSCAP];        // 68 KB staged bucket edges
    __shared__ u32 cnt[BUCKET_SIZE];   // per-local-dst count -> cursor
    __shared__ u32 scn[BUCKET_SIZE];   // scan workspace
    int t = threadIdx.x, b = blockIdx.x;
    u32 e0 = offsets[b];
    u32 len = offsets[b + 1] - e0;
    if (len > LDSCAP) len = LDSCAP;    // safety only; Poisson tail ~0

    cnt[t] = 0;
    __syncthreads();
    for (u32 i = t; i < len; i += STHREADS) {
        u32 e = sorted[e0 + i];
        buf[i] = e;
        atomicAdd(&cnt[e & (BUCKET_SIZE - 1)], 1u);
    }
    __syncthreads();
    u32 v = cnt[t];
    scn[t] = v;
    for (int o = 1; o < BUCKET_SIZE; o <<= 1) {
        __syncthreads();
        u32 u = (t >= o) ? scn[t - o] : 0u;
        __syncthreads();
        scn[t] += u;
    }
    __syncthreads();
    u32 lb = scn[t] - v;               // exclusive local offset
    int node = (b << BUCKET_BITS) + t;
    if (node < N) {
        noff[node] = e0 + lb;
        float di = rsqrtf((float)v + 1.0f);  // +1 self-loop
        dinv[node] = di;
        float2 xv = x[node];
        y[node] = make_float2(di * xv.x, di * xv.y);
    }
    cnt[t] = lb;                       // reuse as placement cursor
    __syncthreads();
    for (u32 i = t; i < len; i += STHREADS) {
        u32 e = buf[i];
        u32 p = atomicAdd(&cnt[e & (BUCKET_SIZE - 1)], 1u);
        sorted[e0 + p] = e >> BUCKET_BITS;   // src-only, grouped by dst node
    }
}

// K6: layer-1 aggregation (thread-per-node, register acc) + fused MLP.
// a = dinv[d]*(sum y[s] + y[d]); h = relu(a W1 + b1); gp = dinv*(h W2)
__global__ void __launch_bounds__(256)
agg1_mlp_kernel(const u32* __restrict__ ssrc, const u32* __restrict__ noff,
                const float2* __restrict__ y, const float* __restrict__ dinv,
                const float* __restrict__ W1, const float* __restrict__ b1,
                const float* __restrict__ W2,
                float2* __restrict__ gp, int N, u32 E) {
    int node = blockIdx.x * blockDim.x + threadIdx.x;
    if (node >= N) return;
    u32 i = noff[node];
    u32 e1 = (node + 1 < N) ? noff[node + 1] : E;
    float2 yv = y[node];
    float sx = yv.x, sy = yv.y;        // self-loop term
    for (; i + 4 <= e1; i += 4) {      // straight-line 4-deep gathers
        u32 s0 = ssrc[i], s1 = ssrc[i + 1], s2 = ssrc[i + 2], s3 = ssrc[i + 3];
        float2 v0 = y[s0], v1 = y[s1], v2 = y[s2], v3 = y[s3];
        sx += (v0.x + v1.x) + (v2.x + v3.x);
        sy += (v0.y + v1.y) + (v2.y + v3.y);
    }
    for (; i < e1; ++i) {
        float2 v = y[ssrc[i]];
        sx += v.x; sy += v.y;
    }
    float di = dinv[node];
    float ax = di * sx, ay = di * sy;
    float g0 = 0.f, g1 = 0.f;
#pragma unroll
    for (int j = 0; j < 16; ++j) {
        float h = fmaf(ax, W1[j], fmaf(ay, W1[16 + j], b1[j]));
        h = fmaxf(h, 0.f);
        g0 = fmaf(h, W2[2 * j], g0);
        g1 = fmaf(h, W2[2 * j + 1], g1);
    }
    gp[node] = make_float2(di * g0, di * g1);
}

// K7: layer-2 aggregation (thread-per-node): out = dinv*(sum gp[s] + gp[d]) + b2
__global__ void __launch_bounds__(256)
agg2_kernel(const u32* __restrict__ ssrc, const u32* __restrict__ noff,
            const float2* __restrict__ gp, const float* __restrict__ dinv,
            const float* __restrict__ b2, float2* __restrict__ out, int N, u32 E) {
    int node = blockIdx.x * blockDim.x + threadIdx.x;
    if (node >= N) return;
    u32 i = noff[node];
    u32 e1 = (node + 1 < N) ? noff[node + 1] : E;
    float2 gv = gp[node];
    float sx = gv.x, sy = gv.y;        // self-loop term
    for (; i + 4 <= e1; i += 4) {
        u32 s0 = ssrc[i], s1 = ssrc[i + 1], s2 = ssrc[i + 2], s3 = ssrc[i + 3];
        float2 v0 = gp[s0], v1 = gp[s1], v2 = gp[s2], v3 = gp[s3];
        sx += (v0.x + v1.x) + (v2.x + v3.x);
        sy += (v0.y + v1.y) + (v2.y + v3.y);
    }
    for (; i < e1; ++i) {
        float2 v = gp[ssrc[i]];
        sx += v.x; sy += v.y;
    }
    float di = dinv[node];
    out[node] = make_float2(fmaf(di, sx, b2[0]), fmaf(di, sy, b2[1]));
}

extern "C" void kernel_launch(void* const* d_in, const int* in_sizes, int n_in,
                              void* d_out, int out_size, void* d_ws, size_t ws_size,
                              hipStream_t stream) {
    const float2* x  = (const float2*)d_in[0];
    const int*    ei = (const int*)d_in[1];   // [2, E]: src row then dst row
    const float*  W1 = (const float*)d_in[2];
    const float*  b1 = (const float*)d_in[3];
    const float*  W2 = (const float*)d_in[4];
    const float*  b2 = (const float*)d_in[5];

    const int N = in_sizes[0] / 2;
    const int E = in_sizes[1] / 2;
    const int* src = ei;
    const int* dst = ei + E;
    const int nbuck = (N + BUCKET_SIZE - 1) >> BUCKET_BITS;   // 391
    const int NB    = (E + PCHUNK - 1) / PCHUNK;              // 782 (<= 1024)

    // Workspace (~31MB). `part` (NB*nbuck u32 ~1.2MB) aliases y (2N floats):
    // part dead after scatter; y first written by sort2 (later on stream).
    // `sorted` is overwritten in place by sort2 to become `ssrc`.
    u32* sorted   = (u32*)d_ws;                               // E (-> ssrc)
    float* dinv   = (float*)(sorted + E);                     // N
    float* y      = dinv + N;                                 // 2N
    float* gp     = y + 2 * (size_t)N;                        // 2N
    u32* noff     = (u32*)(gp + 2 * (size_t)N);               // N
    u32* cnt      = noff + N;                                 // 512
    u32* offsets  = cnt + MAX_NBUCK;                          // nbuck+1
    u32* part     = (u32*)y;                                  // alias
    float2* out   = (float2*)d_out;

    part_hist_kernel<<<NB, STHREADS, 0, stream>>>(dst, part, E, nbuck);
    colscan_kernel  <<<nbuck, MAX_NB, 0, stream>>>(part, cnt, NB, nbuck);
    offsets_kernel  <<<1, MAX_NBUCK, 0, stream>>>(cnt, offsets, nbuck);
    scatter_kernel  <<<NB, STHREADS, 0, stream>>>(src, dst, part, offsets, sorted, E, nbuck);
    sort2_kernel    <<<nbuck, STHREADS, 0, stream>>>(sorted, offsets, x, noff, dinv,
                                                     (float2*)y, N);
    agg1_mlp_kernel <<<(N + 255) / 256, 256, 0, stream>>>(sorted, noff, (const float2*)y,
                                                          dinv, W1, b1, W2,
                                                          (float2*)gp, N, (u32)E);
    agg2_kernel     <<<(N + 255) / 256, 256, 0, stream>>>(sorted, noff, (const float2*)gp,
                                                          dinv, b2, out, N, (u32)E);
}

// Round 16
// 172.064 us; speedup vs baseline: 2.1877x; 1.2010x over previous
//
#include <hip/hip_runtime.h>

// GCN 2-layer, fully-deterministic two-level sort + register aggregation.
// History: global fp32 atomics EA-bound (r1-2); bucket sort + LDS atomics
// (r5-14, agg stuck ~78us); r15: second-level sort -> thread-per-node register
// aggregation, 206us. r15 lesson: sort2's placement wrote 4B to random
// bucket offsets -> 174MB WRITE for a 25.6MB payload (same 7x amplification
// as r5's scatter). Round-16: permute in LDS, stream out coalesced (the fix
// that worked in r10): pass A count (coalesced read), pass B re-read + place
// src into LDS buf[p], pass C coalesced stream-out. 2x read + 1x write, all
// coalesced.

typedef unsigned int u32;
typedef unsigned short u16;

#define BUCKET_BITS 9
#define BUCKET_SIZE (1 << BUCKET_BITS)   // 512 nodes per bucket
#define MAX_NBUCK 512                    // supports N <= 262144
#define PCHUNK 8192                      // edges per partition chunk
#define STHREADS 512
#define MAX_NB 1024                      // supports E <= 8.4M
#define LDSCAP 17408                     // max edges staged per bucket (68KB)

// K1: per-chunk bucket histogram -> part[c*nbuck + j]  (no global atomics)
__global__ void part_hist_kernel(const int* __restrict__ dst, u32* __restrict__ part,
                                 int E, int nbuck) {
    __shared__ u32 h[MAX_NBUCK];
    int t = threadIdx.x, c = blockIdx.x;
    h[t] = 0;
    __syncthreads();
    int start = c * PCHUNK, end = min(start + PCHUNK, E);
    for (int i = start + t; i < end; i += STHREADS)
        atomicAdd(&h[((u32)dst[i]) >> BUCKET_BITS], 1u);
    __syncthreads();
    for (int j = t; j < nbuck; j += STHREADS)
        part[(size_t)c * nbuck + j] = h[j];
}

// K2: per-bucket exclusive prefix across chunks (in place); totals -> cnt[j]
__global__ void colscan_kernel(u32* __restrict__ part, u32* __restrict__ cnt,
                               int NB, int nbuck) {
    __shared__ u32 s[MAX_NB];
    int t = threadIdx.x, j = blockIdx.x;  // 1024 threads, j < nbuck
    u32 v = (t < NB) ? part[(size_t)t * nbuck + j] : 0u;
    s[t] = v;
    for (int o = 1; o < MAX_NB; o <<= 1) {
        __syncthreads();
        u32 u = (t >= o) ? s[t - o] : 0u;
        __syncthreads();
        s[t] += u;
    }
    __syncthreads();
    if (t < NB) part[(size_t)t * nbuck + j] = s[t] - v;  // exclusive prefix
    if (t == MAX_NB - 1) cnt[j] = s[MAX_NB - 1];         // bucket total
}

// K3: exclusive scan of bucket totals -> offsets[0..nbuck]
__global__ void offsets_kernel(const u32* __restrict__ cnt, u32* __restrict__ offsets,
                               int nbuck) {
    __shared__ u32 s[MAX_NBUCK];
    int t = threadIdx.x;  // 512
    u32 v = (t < nbuck) ? cnt[t] : 0u;
    s[t] = v;
    for (int o = 1; o < MAX_NBUCK; o <<= 1) {
        __syncthreads();
        u32 u = (t >= o) ? s[t - o] : 0u;
        __syncthreads();
        s[t] += u;
    }
    __syncthreads();
    if (t < nbuck) offsets[t + 1] = s[t];
    if (t == 0) offsets[0] = 0;
}

// K4: LDS-reorder scatter, precomputed bases (replay-proven r10-r15)
__global__ void __launch_bounds__(STHREADS)
scatter_kernel(const int* __restrict__ src, const int* __restrict__ dst,
               const u32* __restrict__ part, const u32* __restrict__ offsets,
               u32* __restrict__ sorted, int E, int nbuck) {
    __shared__ u32 pk[PCHUNK];
    __shared__ u16 bk[PCHUNK];
    __shared__ u32 hist[MAX_NBUCK];
    __shared__ u32 scr[MAX_NBUCK];
    __shared__ u32 dadj[MAX_NBUCK];
    int t = threadIdx.x, c = blockIdx.x;
    int start = c * PCHUNK, end = min(start + PCHUNK, E);
    int cntE = end - start;

    hist[t] = 0;
    __syncthreads();
    for (int i = start + t; i < end; i += STHREADS)
        atomicAdd(&hist[((u32)dst[i]) >> BUCKET_BITS], 1u);
    __syncthreads();
    u32 v = hist[t];
    scr[t] = v;
    for (int o = 1; o < MAX_NBUCK; o <<= 1) {
        __syncthreads();
        u32 u = (t >= o) ? scr[t - o] : 0u;
        __syncthreads();
        scr[t] += u;
    }
    __syncthreads();
    u32 lb = scr[t] - v;
    hist[t] = lb;
    if (t < nbuck)
        dadj[t] = offsets[t] + part[(size_t)c * nbuck + t] - lb;
    scr[t] = 0;
    __syncthreads();
    for (int i = start + t; i < end; i += STHREADS) {
        u32 d = (u32)dst[i];
        u32 b = d >> BUCKET_BITS;
        u32 p = hist[b] + atomicAdd(&scr[b], 1u);
        pk[p] = ((u32)src[i] << BUCKET_BITS) | (d & (BUCKET_SIZE - 1));
        bk[p] = (u16)b;
    }
    __syncthreads();
    for (int i = t; i < cntE; i += STHREADS)
        sorted[dadj[bk[i]] + i] = pk[i];
}

// K5: per-bucket second-level counting sort by local dst, coalesced I/O.
// Pass A: count (coalesced read). Scan -> noff/dinv/y. Pass B: re-read +
// place src into LDS buf[p] (random LDS write). Pass C: coalesced stream-out.
__global__ void __launch_bounds__(STHREADS)
sort2_kernel(u32* __restrict__ sorted /* in: packed; out: ssrc */,
             const u32* __restrict__ offsets, const float2* __restrict__ x,
             u32* __restrict__ noff, float* __restrict__ dinv,
             float2* __restrict__ y, int N) {
    __shared__ u32 buf[LDSCAP];        // 68 KB: src values, node-run order
    __shared__ u32 cnt[BUCKET_SIZE];   // per-local-dst count -> cursor
    __shared__ u32 scn[BUCKET_SIZE];   // scan workspace
    int t = threadIdx.x, b = blockIdx.x;
    u32 e0 = offsets[b];
    u32 len = offsets[b + 1] - e0;
    if (len > LDSCAP) len = LDSCAP;    // safety only; Poisson tail ~0

    cnt[t] = 0;
    __syncthreads();
    // Pass A: count local dst (coalesced global read, no staging)
    for (u32 i = t; i < len; i += STHREADS)
        atomicAdd(&cnt[sorted[e0 + i] & (BUCKET_SIZE - 1)], 1u);
    __syncthreads();
    u32 v = cnt[t];
    scn[t] = v;
    for (int o = 1; o < BUCKET_SIZE; o <<= 1) {
        __syncthreads();
        u32 u = (t >= o) ? scn[t - o] : 0u;
        __syncthreads();
        scn[t] += u;
    }
    __syncthreads();
    u32 lb = scn[t] - v;               // exclusive local offset
    int node = (b << BUCKET_BITS) + t;
    if (node < N) {
        noff[node] = e0 + lb;
        float di = rsqrtf((float)v + 1.0f);  // +1 self-loop
        dinv[node] = di;
        float2 xv = x[node];
        y[node] = make_float2(di * xv.x, di * xv.y);
    }
    cnt[t] = lb;                       // reuse as placement cursor
    __syncthreads();
    // Pass B: re-read (coalesced) and place src into LDS at sorted position
    for (u32 i = t; i < len; i += STHREADS) {
        u32 e = sorted[e0 + i];
        u32 p = atomicAdd(&cnt[e & (BUCKET_SIZE - 1)], 1u);
        buf[p] = e >> BUCKET_BITS;
    }
    __syncthreads();
    // Pass C: coalesced stream-out (full-line write combining)
    for (u32 i = t; i < len; i += STHREADS)
        sorted[e0 + i] = buf[i];
}

// K6: layer-1 aggregation (thread-per-node, register acc) + fused MLP.
// a = dinv[d]*(sum y[s] + y[d]); h = relu(a W1 + b1); gp = dinv*(h W2)
__global__ void __launch_bounds__(256)
agg1_mlp_kernel(const u32* __restrict__ ssrc, const u32* __restrict__ noff,
                const float2* __restrict__ y, const float* __restrict__ dinv,
                const float* __restrict__ W1, const float* __restrict__ b1,
                const float* __restrict__ W2,
                float2* __restrict__ gp, int N, u32 E) {
    int node = blockIdx.x * blockDim.x + threadIdx.x;
    if (node >= N) return;
    u32 i = noff[node];
    u32 e1 = (node + 1 < N) ? noff[node + 1] : E;
    float2 yv = y[node];
    float sx = yv.x, sy = yv.y;        // self-loop term
    for (; i + 4 <= e1; i += 4) {      // straight-line 4-deep gathers
        u32 s0 = ssrc[i], s1 = ssrc[i + 1], s2 = ssrc[i + 2], s3 = ssrc[i + 3];
        float2 v0 = y[s0], v1 = y[s1], v2 = y[s2], v3 = y[s3];
        sx += (v0.x + v1.x) + (v2.x + v3.x);
        sy += (v0.y + v1.y) + (v2.y + v3.y);
    }
    for (; i < e1; ++i) {
        float2 v = y[ssrc[i]];
        sx += v.x; sy += v.y;
    }
    float di = dinv[node];
    float ax = di * sx, ay = di * sy;
    float g0 = 0.f, g1 = 0.f;
#pragma unroll
    for (int j = 0; j < 16; ++j) {
        float h = fmaf(ax, W1[j], fmaf(ay, W1[16 + j], b1[j]));
        h = fmaxf(h, 0.f);
        g0 = fmaf(h, W2[2 * j], g0);
        g1 = fmaf(h, W2[2 * j + 1], g1);
    }
    gp[node] = make_float2(di * g0, di * g1);
}

// K7: layer-2 aggregation (thread-per-node): out = dinv*(sum gp[s] + gp[d]) + b2
__global__ void __launch_bounds__(256)
agg2_kernel(const u32* __restrict__ ssrc, const u32* __restrict__ noff,
            const float2* __restrict__ gp, const float* __restrict__ dinv,
            const float* __restrict__ b2, float2* __restrict__ out, int N, u32 E) {
    int node = blockIdx.x * blockDim.x + threadIdx.x;
    if (node >= N) return;
    u32 i = noff[node];
    u32 e1 = (node + 1 < N) ? noff[node + 1] : E;
    float2 gv = gp[node];
    float sx = gv.x, sy = gv.y;        // self-loop term
    for (; i + 4 <= e1; i += 4) {
        u32 s0 = ssrc[i], s1 = ssrc[i + 1], s2 = ssrc[i + 2], s3 = ssrc[i + 3];
        float2 v0 = gp[s0], v1 = gp[s1], v2 = gp[s2], v3 = gp[s3];
        sx += (v0.x + v1.x) + (v2.x + v3.x);
        sy += (v0.y + v1.y) + (v2.y + v3.y);
    }
    for (; i < e1; ++i) {
        float2 v = gp[ssrc[i]];
        sx += v.x; sy += v.y;
    }
    float di = dinv[node];
    out[node] = make_float2(fmaf(di, sx, b2[0]), fmaf(di, sy, b2[1]));
}

extern "C" void kernel_launch(void* const* d_in, const int* in_sizes, int n_in,
                              void* d_out, int out_size, void* d_ws, size_t ws_size,
                              hipStream_t stream) {
    const float2* x  = (const float2*)d_in[0];
    const int*    ei = (const int*)d_in[1];   // [2, E]: src row then dst row
    const float*  W1 = (const float*)d_in[2];
    const float*  b1 = (const float*)d_in[3];
    const float*  W2 = (const float*)d_in[4];
    const float*  b2 = (const float*)d_in[5];

    const int N = in_sizes[0] / 2;
    const int E = in_sizes[1] / 2;
    const int* src = ei;
    const int* dst = ei + E;
    const int nbuck = (N + BUCKET_SIZE - 1) >> BUCKET_BITS;   // 391
    const int NB    = (E + PCHUNK - 1) / PCHUNK;              // 782 (<= 1024)

    // Workspace (~31MB). `part` (NB*nbuck u32 ~1.2MB) aliases y (2N floats):
    // part dead after scatter; y first written by sort2 (later on stream).
    // `sorted` is overwritten in place by sort2 to become `ssrc`.
    u32* sorted   = (u32*)d_ws;                               // E (-> ssrc)
    float* dinv   = (float*)(sorted + E);                     // N
    float* y      = dinv + N;                                 // 2N
    float* gp     = y + 2 * (size_t)N;                        // 2N
    u32* noff     = (u32*)(gp + 2 * (size_t)N);               // N
    u32* cnt      = noff + N;                                 // 512
    u32* offsets  = cnt + MAX_NBUCK;                          // nbuck+1
    u32* part     = (u32*)y;                                  // alias
    float2* out   = (float2*)d_out;

    part_hist_kernel<<<NB, STHREADS, 0, stream>>>(dst, part, E, nbuck);
    colscan_kernel  <<<nbuck, MAX_NB, 0, stream>>>(part, cnt, NB, nbuck);
    offsets_kernel  <<<1, MAX_NBUCK, 0, stream>>>(cnt, offsets, nbuck);
    scatter_kernel  <<<NB, STHREADS, 0, stream>>>(src, dst, part, offsets, sorted, E, nbuck);
    sort2_kernel    <<<nbuck, STHREADS, 0, stream>>>(sorted, offsets, x, noff, dinv,
                                                     (float2*)y, N);
    agg1_mlp_kernel <<<(N + 255) / 256, 256, 0, stream>>>(sorted, noff, (const float2*)y,
                                                          dinv, W1, b1, W2,
                                                          (float2*)gp, N, (u32)E);
    agg2_kernel     <<<(N + 255) / 256, 256, 0, stream>>>(sorted, noff, (const float2*)gp,
                                                          dinv, b2, out, N, (u32)E);
}

// Round 17
// 167.555 us; speedup vs baseline: 2.2466x; 1.0269x over previous
//
#include <hip/hip_runtime.h>

// GCN 2-layer, fully-deterministic two-level sort + register aggregation.
// History: global fp32 atomics EA-bound (r1-2); bucket sort + LDS atomics
// (r5-14); two-level sort + thread-per-node register agg (r15); sort2
// coalesced stream-out (r16, 172us). r16 counters: scatter is top (54us),
// not traffic-bound (33MB WRITE, 1.3x) but LDS-phase-bound (2.47M bank
// conflicts, redundant histogram pass). Round-17: scatter derives its chunk
// bucket counts from `part` (count_c[j] = part[c+1][j]-part[c][j]; colscan
// already computed the prefix) -- histogram pass deleted; placement stores
// the final global address so stream-out is two stride-1 LDS reads.

typedef unsigned int u32;

#define BUCKET_BITS 9
#define BUCKET_SIZE (1 << BUCKET_BITS)   // 512 nodes per bucket
#define MAX_NBUCK 512                    // supports N <= 262144
#define PCHUNK 8192                      // edges per partition chunk
#define STHREADS 512
#define MAX_NB 1024                      // supports E <= 8.4M
#define LDSCAP 17408                     // max edges staged per bucket (68KB)

// K1: per-chunk bucket histogram -> part[c*nbuck + j]  (no global atomics)
__global__ void part_hist_kernel(const int* __restrict__ dst, u32* __restrict__ part,
                                 int E, int nbuck) {
    __shared__ u32 h[MAX_NBUCK];
    int t = threadIdx.x, c = blockIdx.x;
    h[t] = 0;
    __syncthreads();
    int start = c * PCHUNK, end = min(start + PCHUNK, E);
    for (int i = start + t; i < end; i += STHREADS)
        atomicAdd(&h[((u32)dst[i]) >> BUCKET_BITS], 1u);
    __syncthreads();
    for (int j = t; j < nbuck; j += STHREADS)
        part[(size_t)c * nbuck + j] = h[j];
}

// K2: per-bucket exclusive prefix across chunks (in place); totals -> cnt[j]
__global__ void colscan_kernel(u32* __restrict__ part, u32* __restrict__ cnt,
                               int NB, int nbuck) {
    __shared__ u32 s[MAX_NB];
    int t = threadIdx.x, j = blockIdx.x;  // 1024 threads, j < nbuck
    u32 v = (t < NB) ? part[(size_t)t * nbuck + j] : 0u;
    s[t] = v;
    for (int o = 1; o < MAX_NB; o <<= 1) {
        __syncthreads();
        u32 u = (t >= o) ? s[t - o] : 0u;
        __syncthreads();
        s[t] += u;
    }
    __syncthreads();
    if (t < NB) part[(size_t)t * nbuck + j] = s[t] - v;  // exclusive prefix
    if (t == MAX_NB - 1) cnt[j] = s[MAX_NB - 1];         // bucket total
}

// K3: exclusive scan of bucket totals -> offsets[0..nbuck]
__global__ void offsets_kernel(const u32* __restrict__ cnt, u32* __restrict__ offsets,
                               int nbuck) {
    __shared__ u32 s[MAX_NBUCK];
    int t = threadIdx.x;  // 512
    u32 v = (t < nbuck) ? cnt[t] : 0u;
    s[t] = v;
    for (int o = 1; o < MAX_NBUCK; o <<= 1) {
        __syncthreads();
        u32 u = (t >= o) ? s[t - o] : 0u;
        __syncthreads();
        s[t] += u;
    }
    __syncthreads();
    if (t < nbuck) offsets[t + 1] = s[t];
    if (t == 0) offsets[0] = 0;
}

// K4: LDS-reorder scatter. Chunk counts derived from part (no histogram
// pass); placement stores final global address; coalesced stream-out.
__global__ void __launch_bounds__(STHREADS)
scatter_kernel(const int* __restrict__ src, const int* __restrict__ dst,
               const u32* __restrict__ part, const u32* __restrict__ cnt,
               const u32* __restrict__ offsets, u32* __restrict__ sorted,
               int E, int nbuck, int NB) {
    __shared__ u32 pk[PCHUNK];        // packed edges, bucket-ordered
    __shared__ u32 ga[PCHUNK];        // final global address per slot
    __shared__ u32 gbase[MAX_NBUCK];  // offsets[j] + part[c][j]
    __shared__ u32 scr[MAX_NBUCK];    // scan ws -> rank counters
    __shared__ u32 lbase[MAX_NBUCK];  // local exclusive base
    int t = threadIdx.x, c = blockIdx.x;
    int start = c * PCHUNK, end = min(start + PCHUNK, E);
    int cntE = end - start;

    // chunk's bucket count from the colscan'd prefix (no counting pass)
    u32 pc = part[(size_t)c * nbuck + t];                       // t < 512 >= nbuck pads read in-range? t may exceed nbuck-1
    u32 v;
    if (t < nbuck) {
        u32 nx = (c + 1 < NB) ? part[(size_t)(c + 1) * nbuck + t] : cnt[t];
        v = nx - pc;
        gbase[t] = offsets[t] + pc;
    } else {
        v = 0;
        gbase[t] = 0;
    }
    // local exclusive scan of counts (Hillis-Steele over 512)
    scr[t] = v;
    for (int o = 1; o < MAX_NBUCK; o <<= 1) {
        __syncthreads();
        u32 u = (t >= o) ? scr[t - o] : 0u;
        __syncthreads();
        scr[t] += u;
    }
    __syncthreads();
    lbase[t] = scr[t] - v;
    scr[t] = 0;                        // rank counters
    __syncthreads();
    // place edges bucket-ordered into LDS; record final global address
    for (int i = start + t; i < end; i += STHREADS) {
        u32 d = (u32)dst[i];
        u32 b = d >> BUCKET_BITS;
        u32 p = lbase[b] + atomicAdd(&scr[b], 1u);
        pk[p] = ((u32)src[i] << BUCKET_BITS) | (d & (BUCKET_SIZE - 1));
        ga[p] = gbase[b] + (p - lbase[b]);
    }
    __syncthreads();
    // stream-out: stride-1 LDS reads, runs of consecutive global addresses
    for (int i = t; i < cntE; i += STHREADS)
        sorted[ga[i]] = pk[i];
}

// K5: per-bucket second-level counting sort by local dst, coalesced I/O
// (replay-proven r16). Emits noff, dinv, y.
__global__ void __launch_bounds__(STHREADS)
sort2_kernel(u32* __restrict__ sorted /* in: packed; out: ssrc */,
             const u32* __restrict__ offsets, const float2* __restrict__ x,
             u32* __restrict__ noff, float* __restrict__ dinv,
             float2* __restrict__ y, int N) {
    __shared__ u32 buf[LDSCAP];        // 68 KB: src values, node-run order
    __shared__ u32 cnt[BUCKET_SIZE];   // per-local-dst count -> cursor
    __shared__ u32 scn[BUCKET_SIZE];   // scan workspace
    int t = threadIdx.x, b = blockIdx.x;
    u32 e0 = offsets[b];
    u32 len = offsets[b + 1] - e0;
    if (len > LDSCAP) len = LDSCAP;    // safety only; Poisson tail ~0

    cnt[t] = 0;
    __syncthreads();
    for (u32 i = t; i < len; i += STHREADS)
        atomicAdd(&cnt[sorted[e0 + i] & (BUCKET_SIZE - 1)], 1u);
    __syncthreads();
    u32 v = cnt[t];
    scn[t] = v;
    for (int o = 1; o < BUCKET_SIZE; o <<= 1) {
        __syncthreads();
        u32 u = (t >= o) ? scn[t - o] : 0u;
        __syncthreads();
        scn[t] += u;
    }
    __syncthreads();
    u32 lb = scn[t] - v;               // exclusive local offset
    int node = (b << BUCKET_BITS) + t;
    if (node < N) {
        noff[node] = e0 + lb;
        float di = rsqrtf((float)v + 1.0f);  // +1 self-loop
        dinv[node] = di;
        float2 xv = x[node];
        y[node] = make_float2(di * xv.x, di * xv.y);
    }
    cnt[t] = lb;                       // reuse as placement cursor
    __syncthreads();
    for (u32 i = t; i < len; i += STHREADS) {
        u32 e = sorted[e0 + i];
        u32 p = atomicAdd(&cnt[e & (BUCKET_SIZE - 1)], 1u);
        buf[p] = e >> BUCKET_BITS;
    }
    __syncthreads();
    for (u32 i = t; i < len; i += STHREADS)
        sorted[e0 + i] = buf[i];
}

// K6: layer-1 aggregation (thread-per-node, register acc) + fused MLP.
__global__ void __launch_bounds__(256)
agg1_mlp_kernel(const u32* __restrict__ ssrc, const u32* __restrict__ noff,
                const float2* __restrict__ y, const float* __restrict__ dinv,
                const float* __restrict__ W1, const float* __restrict__ b1,
                const float* __restrict__ W2,
                float2* __restrict__ gp, int N, u32 E) {
    int node = blockIdx.x * blockDim.x + threadIdx.x;
    if (node >= N) return;
    u32 i = noff[node];
    u32 e1 = (node + 1 < N) ? noff[node + 1] : E;
    float2 yv = y[node];
    float sx = yv.x, sy = yv.y;        // self-loop term
    for (; i + 4 <= e1; i += 4) {
        u32 s0 = ssrc[i], s1 = ssrc[i + 1], s2 = ssrc[i + 2], s3 = ssrc[i + 3];
        float2 v0 = y[s0], v1 = y[s1], v2 = y[s2], v3 = y[s3];
        sx += (v0.x + v1.x) + (v2.x + v3.x);
        sy += (v0.y + v1.y) + (v2.y + v3.y);
    }
    for (; i < e1; ++i) {
        float2 v = y[ssrc[i]];
        sx += v.x; sy += v.y;
    }
    float di = dinv[node];
    float ax = di * sx, ay = di * sy;
    float g0 = 0.f, g1 = 0.f;
#pragma unroll
    for (int j = 0; j < 16; ++j) {
        float h = fmaf(ax, W1[j], fmaf(ay, W1[16 + j], b1[j]));
        h = fmaxf(h, 0.f);
        g0 = fmaf(h, W2[2 * j], g0);
        g1 = fmaf(h, W2[2 * j + 1], g1);
    }
    gp[node] = make_float2(di * g0, di * g1);
}

// K7: layer-2 aggregation (thread-per-node)
__global__ void __launch_bounds__(256)
agg2_kernel(const u32* __restrict__ ssrc, const u32* __restrict__ noff,
            const float2* __restrict__ gp, const float* __restrict__ dinv,
            const float* __restrict__ b2, float2* __restrict__ out, int N, u32 E) {
    int node = blockIdx.x * blockDim.x + threadIdx.x;
    if (node >= N) return;
    u32 i = noff[node];
    u32 e1 = (node + 1 < N) ? noff[node + 1] : E;
    float2 gv = gp[node];
    float sx = gv.x, sy = gv.y;        // self-loop term
    for (; i + 4 <= e1; i += 4) {
        u32 s0 = ssrc[i], s1 = ssrc[i + 1], s2 = ssrc[i + 2], s3 = ssrc[i + 3];
        float2 v0 = gp[s0], v1 = gp[s1], v2 = gp[s2], v3 = gp[s3];
        sx += (v0.x + v1.x) + (v2.x + v3.x);
        sy += (v0.y + v1.y) + (v2.y + v3.y);
    }
    for (; i < e1; ++i) {
        float2 v = gp[ssrc[i]];
        sx += v.x; sy += v.y;
    }
    float di = dinv[node];
    out[node] = make_float2(fmaf(di, sx, b2[0]), fmaf(di, sy, b2[1]));
}

extern "C" void kernel_launch(void* const* d_in, const int* in_sizes, int n_in,
                              void* d_out, int out_size, void* d_ws, size_t ws_size,
                              hipStream_t stream) {
    const float2* x  = (const float2*)d_in[0];
    const int*    ei = (const int*)d_in[1];   // [2, E]: src row then dst row
    const float*  W1 = (const float*)d_in[2];
    const float*  b1 = (const float*)d_in[3];
    const float*  W2 = (const float*)d_in[4];
    const float*  b2 = (const float*)d_in[5];

    const int N = in_sizes[0] / 2;
    const int E = in_sizes[1] / 2;
    const int* src = ei;
    const int* dst = ei + E;
    const int nbuck = (N + BUCKET_SIZE - 1) >> BUCKET_BITS;   // 391
    const int NB    = (E + PCHUNK - 1) / PCHUNK;              // 782 (<= 1024)

    // Workspace (~31MB). `part` (NB*nbuck u32 ~1.2MB) aliases y (2N floats):
    // part's last reader is scatter; y first written by sort2 (later).
    // `sorted` is overwritten in place by sort2 to become `ssrc`.
    u32* sorted   = (u32*)d_ws;                               // E (-> ssrc)
    float* dinv   = (float*)(sorted + E);                     // N
    float* y      = dinv + N;                                 // 2N
    float* gp     = y + 2 * (size_t)N;                        // 2N
    u32* noff     = (u32*)(gp + 2 * (size_t)N);               // N
    u32* cnt      = noff + N;                                 // 512
    u32* offsets  = cnt + MAX_NBUCK;                          // nbuck+1
    u32* part     = (u32*)y;                                  // alias
    float2* out   = (float2*)d_out;

    part_hist_kernel<<<NB, STHREADS, 0, stream>>>(dst, part, E, nbuck);
    colscan_kernel  <<<nbuck, MAX_NB, 0, stream>>>(part, cnt, NB, nbuck);
    offsets_kernel  <<<1, MAX_NBUCK, 0, stream>>>(cnt, offsets, nbuck);
    scatter_kernel  <<<NB, STHREADS, 0, stream>>>(src, dst, part, cnt, offsets,
                                                  sorted, E, nbuck, NB);
    sort2_kernel    <<<nbuck, STHREADS, 0, stream>>>(sorted, offsets, x, noff, dinv,
                                                     (float2*)y, N);
    agg1_mlp_kernel <<<(N + 255) / 256, 256, 0, stream>>>(sorted, noff, (const float2*)y,
                                                          dinv, W1, b1, W2,
                                                          (float2*)gp, N, (u32)E);
    agg2_kernel     <<<(N + 255) / 256, 256, 0, stream>>>(sorted, noff, (const float2*)gp,
                                                          dinv, b2, out, N, (u32)E);
}

// Round 18
// 146.630 us; speedup vs baseline: 2.5672x; 1.1427x over previous
//
#include <hip/hip_runtime.h>

// GCN 2-layer, fully-deterministic two-level sort + register aggregation.
// History: global fp32 atomics EA-bound (r1-2); bucket sort + LDS atomics
// (r5-14); two-level sort + thread-per-node register agg (r15-17, 167us).
// r17 counters: agg passes 48us each at 23.7% occupancy -- GRID-LIMITED
// (200K threads = 3128 waves on 8192 slots); latency-bound per Little's law.
// Round-18: 4 threads per node (800K threads, full occupancy), contiguous
// quarter-runs per lane, __shfl_xor combine within the 4-lane group, lane 0
// does self-loop + norm (+ fused MLP in layer 1) + store.

typedef unsigned int u32;

#define BUCKET_BITS 9
#define BUCKET_SIZE (1 << BUCKET_BITS)   // 512 nodes per bucket
#define MAX_NBUCK 512                    // supports N <= 262144
#define PCHUNK 8192                      // edges per partition chunk
#define STHREADS 512
#define MAX_NB 1024                      // supports E <= 8.4M
#define LDSCAP 17408                     // max edges staged per bucket (68KB)

// K1: per-chunk bucket histogram -> part[c*nbuck + j]  (no global atomics)
__global__ void part_hist_kernel(const int* __restrict__ dst, u32* __restrict__ part,
                                 int E, int nbuck) {
    __shared__ u32 h[MAX_NBUCK];
    int t = threadIdx.x, c = blockIdx.x;
    h[t] = 0;
    __syncthreads();
    int start = c * PCHUNK, end = min(start + PCHUNK, E);
    for (int i = start + t; i < end; i += STHREADS)
        atomicAdd(&h[((u32)dst[i]) >> BUCKET_BITS], 1u);
    __syncthreads();
    for (int j = t; j < nbuck; j += STHREADS)
        part[(size_t)c * nbuck + j] = h[j];
}

// K2: per-bucket exclusive prefix across chunks (in place); totals -> cnt[j]
__global__ void colscan_kernel(u32* __restrict__ part, u32* __restrict__ cnt,
                               int NB, int nbuck) {
    __shared__ u32 s[MAX_NB];
    int t = threadIdx.x, j = blockIdx.x;  // 1024 threads, j < nbuck
    u32 v = (t < NB) ? part[(size_t)t * nbuck + j] : 0u;
    s[t] = v;
    for (int o = 1; o < MAX_NB; o <<= 1) {
        __syncthreads();
        u32 u = (t >= o) ? s[t - o] : 0u;
        __syncthreads();
        s[t] += u;
    }
    __syncthreads();
    if (t < NB) part[(size_t)t * nbuck + j] = s[t] - v;  // exclusive prefix
    if (t == MAX_NB - 1) cnt[j] = s[MAX_NB - 1];         // bucket total
}

// K3: exclusive scan of bucket totals -> offsets[0..nbuck]
__global__ void offsets_kernel(const u32* __restrict__ cnt, u32* __restrict__ offsets,
                               int nbuck) {
    __shared__ u32 s[MAX_NBUCK];
    int t = threadIdx.x;  // 512
    u32 v = (t < nbuck) ? cnt[t] : 0u;
    s[t] = v;
    for (int o = 1; o < MAX_NBUCK; o <<= 1) {
        __syncthreads();
        u32 u = (t >= o) ? s[t - o] : 0u;
        __syncthreads();
        s[t] += u;
    }
    __syncthreads();
    if (t < nbuck) offsets[t + 1] = s[t];
    if (t == 0) offsets[0] = 0;
}

// K4: LDS-reorder scatter; chunk counts derived from part (replay-proven r17)
__global__ void __launch_bounds__(STHREADS)
scatter_kernel(const int* __restrict__ src, const int* __restrict__ dst,
               const u32* __restrict__ part, const u32* __restrict__ cnt,
               const u32* __restrict__ offsets, u32* __restrict__ sorted,
               int E, int nbuck, int NB) {
    __shared__ u32 pk[PCHUNK];        // packed edges, bucket-ordered
    __shared__ u32 ga[PCHUNK];        // final global address per slot
    __shared__ u32 gbase[MAX_NBUCK];  // offsets[j] + part[c][j]
    __shared__ u32 scr[MAX_NBUCK];    // scan ws -> rank counters
    __shared__ u32 lbase[MAX_NBUCK];  // local exclusive base
    int t = threadIdx.x, c = blockIdx.x;
    int start = c * PCHUNK, end = min(start + PCHUNK, E);
    int cntE = end - start;

    u32 v;
    if (t < nbuck) {
        u32 pc = part[(size_t)c * nbuck + t];
        u32 nx = (c + 1 < NB) ? part[(size_t)(c + 1) * nbuck + t] : cnt[t];
        v = nx - pc;
        gbase[t] = offsets[t] + pc;
    } else {
        v = 0;
        gbase[t] = 0;
    }
    scr[t] = v;
    for (int o = 1; o < MAX_NBUCK; o <<= 1) {
        __syncthreads();
        u32 u = (t >= o) ? scr[t - o] : 0u;
        __syncthreads();
        scr[t] += u;
    }
    __syncthreads();
    lbase[t] = scr[t] - v;
    scr[t] = 0;                        // rank counters
    __syncthreads();
    for (int i = start + t; i < end; i += STHREADS) {
        u32 d = (u32)dst[i];
        u32 b = d >> BUCKET_BITS;
        u32 p = lbase[b] + atomicAdd(&scr[b], 1u);
        pk[p] = ((u32)src[i] << BUCKET_BITS) | (d & (BUCKET_SIZE - 1));
        ga[p] = gbase[b] + (p - lbase[b]);
    }
    __syncthreads();
    for (int i = t; i < cntE; i += STHREADS)
        sorted[ga[i]] = pk[i];
}

// K5: per-bucket second-level counting sort, coalesced I/O (replay-proven r16)
__global__ void __launch_bounds__(STHREADS)
sort2_kernel(u32* __restrict__ sorted /* in: packed; out: ssrc */,
             const u32* __restrict__ offsets, const float2* __restrict__ x,
             u32* __restrict__ noff, float* __restrict__ dinv,
             float2* __restrict__ y, int N) {
    __shared__ u32 buf[LDSCAP];        // 68 KB: src values, node-run order
    __shared__ u32 cnt[BUCKET_SIZE];   // per-local-dst count -> cursor
    __shared__ u32 scn[BUCKET_SIZE];   // scan workspace
    int t = threadIdx.x, b = blockIdx.x;
    u32 e0 = offsets[b];
    u32 len = offsets[b + 1] - e0;
    if (len > LDSCAP) len = LDSCAP;    // safety only; Poisson tail ~0

    cnt[t] = 0;
    __syncthreads();
    for (u32 i = t; i < len; i += STHREADS)
        atomicAdd(&cnt[sorted[e0 + i] & (BUCKET_SIZE - 1)], 1u);
    __syncthreads();
    u32 v = cnt[t];
    scn[t] = v;
    for (int o = 1; o < BUCKET_SIZE; o <<= 1) {
        __syncthreads();
        u32 u = (t >= o) ? scn[t - o] : 0u;
        __syncthreads();
        scn[t] += u;
    }
    __syncthreads();
    u32 lb = scn[t] - v;               // exclusive local offset
    int node = (b << BUCKET_BITS) + t;
    if (node < N) {
        noff[node] = e0 + lb;
        float di = rsqrtf((float)v + 1.0f);  // +1 self-loop
        dinv[node] = di;
        float2 xv = x[node];
        y[node] = make_float2(di * xv.x, di * xv.y);
    }
    cnt[t] = lb;                       // reuse as placement cursor
    __syncthreads();
    for (u32 i = t; i < len; i += STHREADS) {
        u32 e = sorted[e0 + i];
        u32 p = atomicAdd(&cnt[e & (BUCKET_SIZE - 1)], 1u);
        buf[p] = e >> BUCKET_BITS;
    }
    __syncthreads();
    for (u32 i = t; i < len; i += STHREADS)
        sorted[e0 + i] = buf[i];
}

// K6: layer-1 aggregation, 4 lanes per node + __shfl_xor combine + fused MLP
__global__ void __launch_bounds__(256)
agg1_mlp_kernel(const u32* __restrict__ ssrc, const u32* __restrict__ noff,
                const float2* __restrict__ y, const float* __restrict__ dinv,
                const float* __restrict__ W1, const float* __restrict__ b1,
                const float* __restrict__ W2,
                float2* __restrict__ gp, int N, u32 E) {
    int tid = blockIdx.x * blockDim.x + threadIdx.x;
    int node = tid >> 2, sub = tid & 3;
    if (node >= N) return;
    u32 i0 = noff[node];
    u32 e1 = (node + 1 < N) ? noff[node + 1] : E;
    u32 len = e1 - i0;
    u32 i = i0 + (len * (u32)sub) / 4;
    u32 q1 = i0 + (len * (u32)(sub + 1)) / 4;
    float sx = 0.f, sy = 0.f;
    for (; i + 4 <= q1; i += 4) {      // straight-line 4-deep gathers
        u32 s0 = ssrc[i], s1 = ssrc[i + 1], s2 = ssrc[i + 2], s3 = ssrc[i + 3];
        float2 v0 = y[s0], v1 = y[s1], v2 = y[s2], v3 = y[s3];
        sx += (v0.x + v1.x) + (v2.x + v3.x);
        sy += (v0.y + v1.y) + (v2.y + v3.y);
    }
    for (; i < q1; ++i) {
        float2 v = y[ssrc[i]];
        sx += v.x; sy += v.y;
    }
    // combine the 4 lane partials (deterministic order)
    sx += __shfl_xor(sx, 1); sy += __shfl_xor(sy, 1);
    sx += __shfl_xor(sx, 2); sy += __shfl_xor(sy, 2);
    if (sub == 0) {
        float2 yv = y[node];
        float di = dinv[node];
        float ax = di * (sx + yv.x), ay = di * (sy + yv.y);
        float g0 = 0.f, g1 = 0.f;
#pragma unroll
        for (int j = 0; j < 16; ++j) {
            float h = fmaf(ax, W1[j], fmaf(ay, W1[16 + j], b1[j]));
            h = fmaxf(h, 0.f);
            g0 = fmaf(h, W2[2 * j], g0);
            g1 = fmaf(h, W2[2 * j + 1], g1);
        }
        gp[node] = make_float2(di * g0, di * g1);
    }
}

// K7: layer-2 aggregation, 4 lanes per node + __shfl_xor combine
__global__ void __launch_bounds__(256)
agg2_kernel(const u32* __restrict__ ssrc, const u32* __restrict__ noff,
            const float2* __restrict__ gp, const float* __restrict__ dinv,
            const float* __restrict__ b2, float2* __restrict__ out, int N, u32 E) {
    int tid = blockIdx.x * blockDim.x + threadIdx.x;
    int node = tid >> 2, sub = tid & 3;
    if (node >= N) return;
    u32 i0 = noff[node];
    u32 e1 = (node + 1 < N) ? noff[node + 1] : E;
    u32 len = e1 - i0;
    u32 i = i0 + (len * (u32)sub) / 4;
    u32 q1 = i0 + (len * (u32)(sub + 1)) / 4;
    float sx = 0.f, sy = 0.f;
    for (; i + 4 <= q1; i += 4) {
        u32 s0 = ssrc[i], s1 = ssrc[i + 1], s2 = ssrc[i + 2], s3 = ssrc[i + 3];
        float2 v0 = gp[s0], v1 = gp[s1], v2 = gp[s2], v3 = gp[s3];
        sx += (v0.x + v1.x) + (v2.x + v3.x);
        sy += (v0.y + v1.y) + (v2.y + v3.y);
    }
    for (; i < q1; ++i) {
        float2 v = gp[ssrc[i]];
        sx += v.x; sy += v.y;
    }
    sx += __shfl_xor(sx, 1); sy += __shfl_xor(sy, 1);
    sx += __shfl_xor(sx, 2); sy += __shfl_xor(sy, 2);
    if (sub == 0) {
        float2 gv = gp[node];
        float di = dinv[node];
        out[node] = make_float2(fmaf(di, sx + gv.x, b2[0]),
                                fmaf(di, sy + gv.y, b2[1]));
    }
}

extern "C" void kernel_launch(void* const* d_in, const int* in_sizes, int n_in,
                              void* d_out, int out_size, void* d_ws, size_t ws_size,
                              hipStream_t stream) {
    const float2* x  = (const float2*)d_in[0];
    const int*    ei = (const int*)d_in[1];   // [2, E]: src row then dst row
    const float*  W1 = (const float*)d_in[2];
    const float*  b1 = (const float*)d_in[3];
    const float*  W2 = (const float*)d_in[4];
    const float*  b2 = (const float*)d_in[5];

    const int N = in_sizes[0] / 2;
    const int E = in_sizes[1] / 2;
    const int* src = ei;
    const int* dst = ei + E;
    const int nbuck = (N + BUCKET_SIZE - 1) >> BUCKET_BITS;   // 391
    const int NB    = (E + PCHUNK - 1) / PCHUNK;              // 782 (<= 1024)

    // Workspace (~31MB). `part` aliases y (dead before sort2 writes y);
    // `sorted` overwritten in place by sort2 to become `ssrc`.
    u32* sorted   = (u32*)d_ws;                               // E (-> ssrc)
    float* dinv   = (float*)(sorted + E);                     // N
    float* y      = dinv + N;                                 // 2N
    float* gp     = y + 2 * (size_t)N;                        // 2N
    u32* noff     = (u32*)(gp + 2 * (size_t)N);               // N
    u32* cnt      = noff + N;                                 // 512
    u32* offsets  = cnt + MAX_NBUCK;                          // nbuck+1
    u32* part     = (u32*)y;                                  // alias
    float2* out   = (float2*)d_out;

    part_hist_kernel<<<NB, STHREADS, 0, stream>>>(dst, part, E, nbuck);
    colscan_kernel  <<<nbuck, MAX_NB, 0, stream>>>(part, cnt, NB, nbuck);
    offsets_kernel  <<<1, MAX_NBUCK, 0, stream>>>(cnt, offsets, nbuck);
    scatter_kernel  <<<NB, STHREADS, 0, stream>>>(src, dst, part, cnt, offsets,
                                                  sorted, E, nbuck, NB);
    sort2_kernel    <<<nbuck, STHREADS, 0, stream>>>(sorted, offsets, x, noff, dinv,
                                                     (float2*)y, N);
    agg1_mlp_kernel <<<(4 * N + 255) / 256, 256, 0, stream>>>(sorted, noff,
                                                              (const float2*)y, dinv,
                                                              W1, b1, W2,
                                                              (float2*)gp, N, (u32)E);
    agg2_kernel     <<<(4 * N + 255) / 256, 256, 0, stream>>>(sorted, noff,
                                                              (const float2*)gp, dinv,
                                                              b2, out, N, (u32)E);
}

// Round 19
// 142.101 us; speedup vs baseline: 2.6490x; 1.0319x over previous
//
#include <hip/hip_runtime.h>

// GCN 2-layer, fully-deterministic two-level sort + register aggregation.
// History: global fp32 atomics EA-bound (r1-2); bucket sort + LDS atomics
// (r5-14); two-level sort + thread/lane-per-node register agg (r15-18,
// 146.6us). r18 counters: scatter top (46us), 18 block-barriers in the
// 512-wide scan + 70KB LDS (2 blocks/CU). Round-19: wave-shuffle scans
// (18 -> 2 barriers), bk-u16 + packed lbase|rank (52KB -> 3 blocks/CU),
// aggs at 8 lanes/node, sort2 scan de-barriered. All block-local changes;
// every buffer remains a pure function of the inputs.

typedef unsigned int u32;
typedef unsigned short u16;

#define BUCKET_BITS 9
#define BUCKET_SIZE (1 << BUCKET_BITS)   // 512 nodes per bucket
#define MAX_NBUCK 512                    // supports N <= 262144
#define PCHUNK 8192                      // edges per partition chunk
#define STHREADS 512
#define MAX_NB 1024                      // supports E <= 8.4M
#define LDSCAP 17408                     // max edges staged per bucket (68KB)

// K1: per-chunk bucket histogram -> part[c*nbuck + j]  (no global atomics)
__global__ void part_hist_kernel(const int* __restrict__ dst, u32* __restrict__ part,
                                 int E, int nbuck) {
    __shared__ u32 h[MAX_NBUCK];
    int t = threadIdx.x, c = blockIdx.x;
    h[t] = 0;
    __syncthreads();
    int start = c * PCHUNK, end = min(start + PCHUNK, E);
    for (int i = start + t; i < end; i += STHREADS)
        atomicAdd(&h[((u32)dst[i]) >> BUCKET_BITS], 1u);
    __syncthreads();
    for (int j = t; j < nbuck; j += STHREADS)
        part[(size_t)c * nbuck + j] = h[j];
}

// K2: per-bucket exclusive prefix across chunks (in place); totals -> cnt[j]
__global__ void colscan_kernel(u32* __restrict__ part, u32* __restrict__ cnt,
                               int NB, int nbuck) {
    __shared__ u32 s[MAX_NB];
    int t = threadIdx.x, j = blockIdx.x;  // 1024 threads, j < nbuck
    u32 v = (t < NB) ? part[(size_t)t * nbuck + j] : 0u;
    s[t] = v;
    for (int o = 1; o < MAX_NB; o <<= 1) {
        __syncthreads();
        u32 u = (t >= o) ? s[t - o] : 0u;
        __syncthreads();
        s[t] += u;
    }
    __syncthreads();
    if (t < NB) part[(size_t)t * nbuck + j] = s[t] - v;  // exclusive prefix
    if (t == MAX_NB - 1) cnt[j] = s[MAX_NB - 1];         // bucket total
}

// K3: exclusive scan of bucket totals -> offsets[0..nbuck]
__global__ void offsets_kernel(const u32* __restrict__ cnt, u32* __restrict__ offsets,
                               int nbuck) {
    __shared__ u32 s[MAX_NBUCK];
    int t = threadIdx.x;  // 512
    u32 v = (t < nbuck) ? cnt[t] : 0u;
    s[t] = v;
    for (int o = 1; o < MAX_NBUCK; o <<= 1) {
        __syncthreads();
        u32 u = (t >= o) ? s[t - o] : 0u;
        __syncthreads();
        s[t] += u;
    }
    __syncthreads();
    if (t < nbuck) offsets[t + 1] = s[t];
    if (t == 0) offsets[0] = 0;
}

// Block-wide exclusive scan helper pieces (wave shuffle): returns exclusive
// prefix of v over 512 threads using 2 barriers.
__device__ __forceinline__ u32 block_exscan512(u32 v, u32* wtot /*>=8 u32 LDS*/) {
    int t = threadIdx.x, lane = t & 63, wid = t >> 6;
    u32 x = v;
#pragma unroll
    for (int d = 1; d < 64; d <<= 1) {
        u32 u = __shfl_up(x, d);
        if (lane >= d) x += u;
    }
    if (lane == 63) wtot[wid] = x;
    __syncthreads();
    u32 woff = 0;
#pragma unroll
    for (int w = 0; w < 8; ++w) {
        u32 wv = wtot[w];
        woff += (w < wid) ? wv : 0u;
    }
    __syncthreads();   // wtot reusable after this
    return woff + x - v;
}

// K4: LDS-reorder scatter. Chunk counts derived from part; wave-shuffle scan
// (2 barriers); packed lbase<<16|rank; bk u16 + dadj for stream-out. 52KB LDS.
__global__ void __launch_bounds__(STHREADS)
scatter_kernel(const int* __restrict__ src, const int* __restrict__ dst,
               const u32* __restrict__ part, const u32* __restrict__ cnt,
               const u32* __restrict__ offsets, u32* __restrict__ sorted,
               int E, int nbuck, int NB) {
    __shared__ u32 pk[PCHUNK];        // 32KB packed edges, bucket-ordered
    __shared__ u16 bk[PCHUNK];        // 16KB bucket id per slot
    __shared__ u32 scr[MAX_NBUCK];    // 2KB: (lbase<<16) | rank
    __shared__ u32 dadj[MAX_NBUCK];   // 2KB: global_base - lbase
    __shared__ u32 wtot[8];
    int t = threadIdx.x, c = blockIdx.x;
    int start = c * PCHUNK, end = min(start + PCHUNK, E);
    int cntE = end - start;

    u32 v = 0, gb = 0;
    if (t < nbuck) {
        u32 pc = part[(size_t)c * nbuck + t];
        u32 nx = (c + 1 < NB) ? part[(size_t)(c + 1) * nbuck + t] : cnt[t];
        v = nx - pc;
        gb = offsets[t] + pc;
    }
    u32 lb = block_exscan512(v, wtot);
    scr[t] = lb << 16;                 // rank starts at 0
    dadj[t] = gb - lb;                 // only consulted for t < nbuck
    __syncthreads();
    for (int i = start + t; i < end; i += STHREADS) {
        u32 d = (u32)dst[i];
        u32 b = d >> BUCKET_BITS;
        u32 old = atomicAdd(&scr[b], 1u);
        u32 p = (old >> 16) + (old & 0xFFFFu);
        pk[p] = ((u32)src[i] << BUCKET_BITS) | (d & (BUCKET_SIZE - 1));
        bk[p] = (u16)b;
    }
    __syncthreads();
    for (int i = t; i < cntE; i += STHREADS)
        sorted[dadj[bk[i]] + i] = pk[i];
}

// K5: per-bucket second-level counting sort, coalesced I/O, wave-shuffle scan.
__global__ void __launch_bounds__(STHREADS)
sort2_kernel(u32* __restrict__ sorted /* in: packed; out: ssrc */,
             const u32* __restrict__ offsets, const float2* __restrict__ x,
             u32* __restrict__ noff, float* __restrict__ dinv,
             float2* __restrict__ y, int N) {
    __shared__ u32 buf[LDSCAP];        // 68 KB: src values, node-run order
    __shared__ u32 cnt[BUCKET_SIZE];   // per-local-dst count -> cursor
    __shared__ u32 wtot[8];
    int t = threadIdx.x, b = blockIdx.x;
    u32 e0 = offsets[b];
    u32 len = offsets[b + 1] - e0;
    if (len > LDSCAP) len = LDSCAP;    // safety only; Poisson tail ~0

    cnt[t] = 0;
    __syncthreads();
    for (u32 i = t; i < len; i += STHREADS)
        atomicAdd(&cnt[sorted[e0 + i] & (BUCKET_SIZE - 1)], 1u);
    __syncthreads();
    u32 v = cnt[t];
    u32 lb = block_exscan512(v, wtot);
    int node = (b << BUCKET_BITS) + t;
    if (node < N) {
        noff[node] = e0 + lb;
        float di = rsqrtf((float)v + 1.0f);  // +1 self-loop
        dinv[node] = di;
        float2 xv = x[node];
        y[node] = make_float2(di * xv.x, di * xv.y);
    }
    cnt[t] = lb;                       // reuse as placement cursor
    __syncthreads();
    for (u32 i = t; i < len; i += STHREADS) {
        u32 e = sorted[e0 + i];
        u32 p = atomicAdd(&cnt[e & (BUCKET_SIZE - 1)], 1u);
        buf[p] = e >> BUCKET_BITS;
    }
    __syncthreads();
    for (u32 i = t; i < len; i += STHREADS)
        sorted[e0 + i] = buf[i];
}

// K6: layer-1 aggregation, 8 lanes per node + __shfl_xor combine + fused MLP
__global__ void __launch_bounds__(256)
agg1_mlp_kernel(const u32* __restrict__ ssrc, const u32* __restrict__ noff,
                const float2* __restrict__ y, const float* __restrict__ dinv,
                const float* __restrict__ W1, const float* __restrict__ b1,
                const float* __restrict__ W2,
                float2* __restrict__ gp, int N, u32 E) {
    int tid = blockIdx.x * blockDim.x + threadIdx.x;
    int node = tid >> 3, sub = tid & 7;
    if (node >= N) return;
    u32 i0 = noff[node];
    u32 e1 = (node + 1 < N) ? noff[node + 1] : E;
    u32 len = e1 - i0;
    u32 i = i0 + (len * (u32)sub) / 8;
    u32 q1 = i0 + (len * (u32)(sub + 1)) / 8;
    float sx = 0.f, sy = 0.f;
    for (; i + 4 <= q1; i += 4) {
        u32 s0 = ssrc[i], s1 = ssrc[i + 1], s2 = ssrc[i + 2], s3 = ssrc[i + 3];
        float2 v0 = y[s0], v1 = y[s1], v2 = y[s2], v3 = y[s3];
        sx += (v0.x + v1.x) + (v2.x + v3.x);
        sy += (v0.y + v1.y) + (v2.y + v3.y);
    }
    for (; i < q1; ++i) {
        float2 v = y[ssrc[i]];
        sx += v.x; sy += v.y;
    }
    // combine the 8 lane partials (within-wave groups, deterministic)
    sx += __shfl_xor(sx, 1); sy += __shfl_xor(sy, 1);
    sx += __shfl_xor(sx, 2); sy += __shfl_xor(sy, 2);
    sx += __shfl_xor(sx, 4); sy += __shfl_xor(sy, 4);
    if (sub == 0) {
        float2 yv = y[node];
        float di = dinv[node];
        float ax = di * (sx + yv.x), ay = di * (sy + yv.y);
        float g0 = 0.f, g1 = 0.f;
#pragma unroll
        for (int j = 0; j < 16; ++j) {
            float h = fmaf(ax, W1[j], fmaf(ay, W1[16 + j], b1[j]));
            h = fmaxf(h, 0.f);
            g0 = fmaf(h, W2[2 * j], g0);
            g1 = fmaf(h, W2[2 * j + 1], g1);
        }
        gp[node] = make_float2(di * g0, di * g1);
    }
}

// K7: layer-2 aggregation, 8 lanes per node + __shfl_xor combine
__global__ void __launch_bounds__(256)
agg2_kernel(const u32* __restrict__ ssrc, const u32* __restrict__ noff,
            const float2* __restrict__ gp, const float* __restrict__ dinv,
            const float* __restrict__ b2, float2* __restrict__ out, int N, u32 E) {
    int tid = blockIdx.x * blockDim.x + threadIdx.x;
    int node = tid >> 3, sub = tid & 7;
    if (node >= N) return;
    u32 i0 = noff[node];
    u32 e1 = (node + 1 < N) ? noff[node + 1] : E;
    u32 len = e1 - i0;
    u32 i = i0 + (len * (u32)sub) / 8;
    u32 q1 = i0 + (len * (u32)(sub + 1)) / 8;
    float sx = 0.f, sy = 0.f;
    for (; i + 4 <= q1; i += 4) {
        u32 s0 = ssrc[i], s1 = ssrc[i + 1], s2 = ssrc[i + 2], s3 = ssrc[i + 3];
        float2 v0 = gp[s0], v1 = gp[s1], v2 = gp[s2], v3 = gp[s3];
        sx += (v0.x + v1.x) + (v2.x + v3.x);
        sy += (v0.y + v1.y) + (v2.y + v3.y);
    }
    for (; i < q1; ++i) {
        float2 v = gp[ssrc[i]];
        sx += v.x; sy += v.y;
    }
    sx += __shfl_xor(sx, 1); sy += __shfl_xor(sy, 1);
    sx += __shfl_xor(sx, 2); sy += __shfl_xor(sy, 2);
    sx += __shfl_xor(sx, 4); sy += __shfl_xor(sy, 4);
    if (sub == 0) {
        float2 gv = gp[node];
        float di = dinv[node];
        out[node] = make_float2(fmaf(di, sx + gv.x, b2[0]),
                                fmaf(di, sy + gv.y, b2[1]));
    }
}

extern "C" void kernel_launch(void* const* d_in, const int* in_sizes, int n_in,
                              void* d_out, int out_size, void* d_ws, size_t ws_size,
                              hipStream_t stream) {
    const float2* x  = (const float2*)d_in[0];
    const int*    ei = (const int*)d_in[1];   // [2, E]: src row then dst row
    const float*  W1 = (const float*)d_in[2];
    const float*  b1 = (const float*)d_in[3];
    const float*  W2 = (const float*)d_in[4];
    const float*  b2 = (const float*)d_in[5];

    const int N = in_sizes[0] / 2;
    const int E = in_sizes[1] / 2;
    const int* src = ei;
    const int* dst = ei + E;
    const int nbuck = (N + BUCKET_SIZE - 1) >> BUCKET_BITS;   // 391
    const int NB    = (E + PCHUNK - 1) / PCHUNK;              // 782 (<= 1024)

    // Workspace (~31MB). `part` aliases y (dead before sort2 writes y);
    // `sorted` overwritten in place by sort2 to become `ssrc`.
    u32* sorted   = (u32*)d_ws;                               // E (-> ssrc)
    float* dinv   = (float*)(sorted + E);                     // N
    float* y      = dinv + N;                                 // 2N
    float* gp     = y + 2 * (size_t)N;                        // 2N
    u32* noff     = (u32*)(gp + 2 * (size_t)N);               // N
    u32* cnt      = noff + N;                                 // 512
    u32* offsets  = cnt + MAX_NBUCK;                          // nbuck+1
    u32* part     = (u32*)y;                                  // alias
    float2* out   = (float2*)d_out;

    part_hist_kernel<<<NB, STHREADS, 0, stream>>>(dst, part, E, nbuck);
    colscan_kernel  <<<nbuck, MAX_NB, 0, stream>>>(part, cnt, NB, nbuck);
    offsets_kernel  <<<1, MAX_NBUCK, 0, stream>>>(cnt, offsets, nbuck);
    scatter_kernel  <<<NB, STHREADS, 0, stream>>>(src, dst, part, cnt, offsets,
                                                  sorted, E, nbuck, NB);
    sort2_kernel    <<<nbuck, STHREADS, 0, stream>>>(sorted, offsets, x, noff, dinv,
                                                     (float2*)y, N);
    agg1_mlp_kernel <<<(8 * N + 255) / 256, 256, 0, stream>>>(sorted, noff,
                                                              (const float2*)y, dinv,
                                                              W1, b1, W2,
                                                              (float2*)gp, N, (u32)E);
    agg2_kernel     <<<(8 * N + 255) / 256, 256, 0, stream>>>(sorted, noff,
                                                              (const float2*)gp, dinv,
                                                              b2, out, N, (u32)E);
}

// Round 20
// 127.328 us; speedup vs baseline: 2.9564x; 1.1160x over previous
//
#include <hip/hip_runtime.h>

// GCN 2-layer, fully-deterministic two-level sort + register aggregation.
// History: global fp32 atomics EA-bound (r1-2); bucket sort + LDS atomics
// (r5-14); two-level sort + lane-per-node register agg (r15-19, 142us).
// r19 counters: scatter 40us at 30% occupancy, VALU 7% -- latency-bound on
// 16 serial LDS-chain iterations/thread; sort2 grid-limited (391x8 waves).
// Round-20: 1024-thread blocks for part_hist/scatter/sort2 (half the serial
// depth per thread, 32 waves/CU for scatter), 16-wave shuffle scan.
// All block-local; buffers remain pure functions of inputs.

typedef unsigned int u32;
typedef unsigned short u16;

#define BUCKET_BITS 9
#define BUCKET_SIZE (1 << BUCKET_BITS)   // 512 nodes per bucket
#define MAX_NBUCK 512                    // supports N <= 262144
#define PCHUNK 8192                      // edges per partition chunk
#define BT 1024                          // big-block threads
#define MAX_NB 1024                      // supports E <= 8.4M
#define LDSCAP 17408                     // max edges staged per bucket (68KB)

// K1: per-chunk bucket histogram -> part[c*nbuck + j]  (no global atomics)
__global__ void __launch_bounds__(BT)
part_hist_kernel(const int* __restrict__ dst, u32* __restrict__ part,
                 int E, int nbuck) {
    __shared__ u32 h[MAX_NBUCK];
    int t = threadIdx.x, c = blockIdx.x;
    if (t < MAX_NBUCK) h[t] = 0;
    __syncthreads();
    int start = c * PCHUNK, end = min(start + PCHUNK, E);
    for (int i = start + t; i < end; i += BT)
        atomicAdd(&h[((u32)dst[i]) >> BUCKET_BITS], 1u);
    __syncthreads();
    if (t < nbuck) part[(size_t)c * nbuck + t] = h[t];
}

// K2: per-bucket exclusive prefix across chunks (in place); totals -> cnt[j]
__global__ void colscan_kernel(u32* __restrict__ part, u32* __restrict__ cnt,
                               int NB, int nbuck) {
    __shared__ u32 s[MAX_NB];
    int t = threadIdx.x, j = blockIdx.x;  // 1024 threads, j < nbuck
    u32 v = (t < NB) ? part[(size_t)t * nbuck + j] : 0u;
    s[t] = v;
    for (int o = 1; o < MAX_NB; o <<= 1) {
        __syncthreads();
        u32 u = (t >= o) ? s[t - o] : 0u;
        __syncthreads();
        s[t] += u;
    }
    __syncthreads();
    if (t < NB) part[(size_t)t * nbuck + j] = s[t] - v;  // exclusive prefix
    if (t == MAX_NB - 1) cnt[j] = s[MAX_NB - 1];         // bucket total
}

// K3: exclusive scan of bucket totals -> offsets[0..nbuck]
__global__ void offsets_kernel(const u32* __restrict__ cnt, u32* __restrict__ offsets,
                               int nbuck) {
    __shared__ u32 s[MAX_NBUCK];
    int t = threadIdx.x;  // 512
    u32 v = (t < nbuck) ? cnt[t] : 0u;
    s[t] = v;
    for (int o = 1; o < MAX_NBUCK; o <<= 1) {
        __syncthreads();
        u32 u = (t >= o) ? s[t - o] : 0u;
        __syncthreads();
        s[t] += u;
    }
    __syncthreads();
    if (t < nbuck) offsets[t + 1] = s[t];
    if (t == 0) offsets[0] = 0;
}

// Block-wide exclusive scan over BT=1024 threads (16 waves, 2 barriers)
__device__ __forceinline__ u32 block_exscan16(u32 v, u32* wtot /*>=16 u32 LDS*/) {
    int t = threadIdx.x, lane = t & 63, wid = t >> 6;
    u32 x = v;
#pragma unroll
    for (int d = 1; d < 64; d <<= 1) {
        u32 u = __shfl_up(x, d);
        if (lane >= d) x += u;
    }
    if (lane == 63) wtot[wid] = x;
    __syncthreads();
    u32 woff = 0;
#pragma unroll
    for (int w = 0; w < 16; ++w) {
        u32 wv = wtot[w];
        woff += (w < wid) ? wv : 0u;
    }
    __syncthreads();   // wtot reusable after this
    return woff + x - v;
}

// K4: LDS-reorder scatter. Chunk counts derived from part; 16-wave shuffle
// scan; packed lbase<<16|rank; bk u16 + dadj stream-out. 52KB LDS, 1024 thr.
__global__ void __launch_bounds__(BT)
scatter_kernel(const int* __restrict__ src, const int* __restrict__ dst,
               const u32* __restrict__ part, const u32* __restrict__ cnt,
               const u32* __restrict__ offsets, u32* __restrict__ sorted,
               int E, int nbuck, int NB) {
    __shared__ u32 pk[PCHUNK];        // 32KB packed edges, bucket-ordered
    __shared__ u16 bk[PCHUNK];        // 16KB bucket id per slot
    __shared__ u32 scr[MAX_NBUCK];    // 2KB: (lbase<<16) | rank
    __shared__ u32 dadj[MAX_NBUCK];   // 2KB: global_base - lbase
    __shared__ u32 wtot[16];
    int t = threadIdx.x, c = blockIdx.x;
    int start = c * PCHUNK, end = min(start + PCHUNK, E);
    int cntE = end - start;

    u32 v = 0, gb = 0;
    if (t < nbuck) {
        u32 pc = part[(size_t)c * nbuck + t];
        u32 nx = (c + 1 < NB) ? part[(size_t)(c + 1) * nbuck + t] : cnt[t];
        v = nx - pc;
        gb = offsets[t] + pc;
    }
    u32 lb = block_exscan16(v, wtot);
    if (t < MAX_NBUCK) {
        scr[t] = lb << 16;             // rank starts at 0
        dadj[t] = gb - lb;             // only consulted for t < nbuck
    }
    __syncthreads();
    for (int i = start + t; i < end; i += BT) {
        u32 d = (u32)dst[i];
        u32 b = d >> BUCKET_BITS;
        u32 old = atomicAdd(&scr[b], 1u);
        u32 p = (old >> 16) + (old & 0xFFFFu);
        pk[p] = ((u32)src[i] << BUCKET_BITS) | (d & (BUCKET_SIZE - 1));
        bk[p] = (u16)b;
    }
    __syncthreads();
    for (int i = t; i < cntE; i += BT)
        sorted[dadj[bk[i]] + i] = pk[i];
}

// K5: per-bucket second-level counting sort, coalesced I/O, 1024 threads.
__global__ void __launch_bounds__(BT)
sort2_kernel(u32* __restrict__ sorted /* in: packed; out: ssrc */,
             const u32* __restrict__ offsets, const float2* __restrict__ x,
             u32* __restrict__ noff, float* __restrict__ dinv,
             float2* __restrict__ y, int N) {
    __shared__ u32 buf[LDSCAP];        // 68 KB: src values, node-run order
    __shared__ u32 cnt[BUCKET_SIZE];   // per-local-dst count -> cursor
    __shared__ u32 wtot[16];
    int t = threadIdx.x, b = blockIdx.x;
    u32 e0 = offsets[b];
    u32 len = offsets[b + 1] - e0;
    if (len > LDSCAP) len = LDSCAP;    // safety only; Poisson tail ~0

    if (t < BUCKET_SIZE) cnt[t] = 0;
    __syncthreads();
    for (u32 i = t; i < len; i += BT)
        atomicAdd(&cnt[sorted[e0 + i] & (BUCKET_SIZE - 1)], 1u);
    __syncthreads();
    u32 v = (t < BUCKET_SIZE) ? cnt[t] : 0u;
    u32 lb = block_exscan16(v, wtot);
    int node = (b << BUCKET_BITS) + t;
    if (t < BUCKET_SIZE && node < N) {
        noff[node] = e0 + lb;
        float di = rsqrtf((float)v + 1.0f);  // +1 self-loop
        dinv[node] = di;
        float2 xv = x[node];
        y[node] = make_float2(di * xv.x, di * xv.y);
    }
    if (t < BUCKET_SIZE) cnt[t] = lb;  // reuse as placement cursor
    __syncthreads();
    for (u32 i = t; i < len; i += BT) {
        u32 e = sorted[e0 + i];
        u32 p = atomicAdd(&cnt[e & (BUCKET_SIZE - 1)], 1u);
        buf[p] = e >> BUCKET_BITS;
    }
    __syncthreads();
    for (u32 i = t; i < len; i += BT)
        sorted[e0 + i] = buf[i];
}

// K6: layer-1 aggregation, 8 lanes per node + __shfl_xor combine + fused MLP
__global__ void __launch_bounds__(256)
agg1_mlp_kernel(const u32* __restrict__ ssrc, const u32* __restrict__ noff,
                const float2* __restrict__ y, const float* __restrict__ dinv,
                const float* __restrict__ W1, const float* __restrict__ b1,
                const float* __restrict__ W2,
                float2* __restrict__ gp, int N, u32 E) {
    int tid = blockIdx.x * blockDim.x + threadIdx.x;
    int node = tid >> 3, sub = tid & 7;
    if (node >= N) return;
    u32 i0 = noff[node];
    u32 e1 = (node + 1 < N) ? noff[node + 1] : E;
    u32 len = e1 - i0;
    u32 i = i0 + (len * (u32)sub) / 8;
    u32 q1 = i0 + (len * (u32)(sub + 1)) / 8;
    float sx = 0.f, sy = 0.f;
    for (; i + 4 <= q1; i += 4) {
        u32 s0 = ssrc[i], s1 = ssrc[i + 1], s2 = ssrc[i + 2], s3 = ssrc[i + 3];
        float2 v0 = y[s0], v1 = y[s1], v2 = y[s2], v3 = y[s3];
        sx += (v0.x + v1.x) + (v2.x + v3.x);
        sy += (v0.y + v1.y) + (v2.y + v3.y);
    }
    for (; i < q1; ++i) {
        float2 v = y[ssrc[i]];
        sx += v.x; sy += v.y;
    }
    sx += __shfl_xor(sx, 1); sy += __shfl_xor(sy, 1);
    sx += __shfl_xor(sx, 2); sy += __shfl_xor(sy, 2);
    sx += __shfl_xor(sx, 4); sy += __shfl_xor(sy, 4);
    if (sub == 0) {
        float2 yv = y[node];
        float di = dinv[node];
        float ax = di * (sx + yv.x), ay = di * (sy + yv.y);
        float g0 = 0.f, g1 = 0.f;
#pragma unroll
        for (int j = 0; j < 16; ++j) {
            float h = fmaf(ax, W1[j], fmaf(ay, W1[16 + j], b1[j]));
            h = fmaxf(h, 0.f);
            g0 = fmaf(h, W2[2 * j], g0);
            g1 = fmaf(h, W2[2 * j + 1], g1);
        }
        gp[node] = make_float2(di * g0, di * g1);
    }
}

// K7: layer-2 aggregation, 8 lanes per node + __shfl_xor combine
__global__ void __launch_bounds__(256)
agg2_kernel(const u32* __restrict__ ssrc, const u32* __restrict__ noff,
            const float2* __restrict__ gp, const float* __restrict__ dinv,
            const float* __restrict__ b2, float2* __restrict__ out, int N, u32 E) {
    int tid = blockIdx.x * blockDim.x + threadIdx.x;
    int node = tid >> 3, sub = tid & 7;
    if (node >= N) return;
    u32 i0 = noff[node];
    u32 e1 = (node + 1 < N) ? noff[node + 1] : E;
    u32 len = e1 - i0;
    u32 i = i0 + (len * (u32)sub) / 8;
    u32 q1 = i0 + (len * (u32)(sub + 1)) / 8;
    float sx = 0.f, sy = 0.f;
    for (; i + 4 <= q1; i += 4) {
        u32 s0 = ssrc[i], s1 = ssrc[i + 1], s2 = ssrc[i + 2], s3 = ssrc[i + 3];
        float2 v0 = gp[s0], v1 = gp[s1], v2 = gp[s2], v3 = gp[s3];
        sx += (v0.x + v1.x) + (v2.x + v3.x);
        sy += (v0.y + v1.y) + (v2.y + v3.y);
    }
    for (; i < q1; ++i) {
        float2 v = gp[ssrc[i]];
        sx += v.x; sy += v.y;
    }
    sx += __shfl_xor(sx, 1); sy += __shfl_xor(sy, 1);
    sx += __shfl_xor(sx, 2); sy += __shfl_xor(sy, 2);
    sx += __shfl_xor(sx, 4); sy += __shfl_xor(sy, 4);
    if (sub == 0) {
        float2 gv = gp[node];
        float di = dinv[node];
        out[node] = make_float2(fmaf(di, sx + gv.x, b2[0]),
                                fmaf(di, sy + gv.y, b2[1]));
    }
}

extern "C" void kernel_launch(void* const* d_in, const int* in_sizes, int n_in,
                              void* d_out, int out_size, void* d_ws, size_t ws_size,
                              hipStream_t stream) {
    const float2* x  = (const float2*)d_in[0];
    const int*    ei = (const int*)d_in[1];   // [2, E]: src row then dst row
    const float*  W1 = (const float*)d_in[2];
    const float*  b1 = (const float*)d_in[3];
    const float*  W2 = (const float*)d_in[4];
    const float*  b2 = (const float*)d_in[5];

    const int N = in_sizes[0] / 2;
    const int E = in_sizes[1] / 2;
    const int* src = ei;
    const int* dst = ei + E;
    const int nbuck = (N + BUCKET_SIZE - 1) >> BUCKET_BITS;   // 391
    const int NB    = (E + PCHUNK - 1) / PCHUNK;              // 782 (<= 1024)

    // Workspace (~31MB). `part` aliases y (dead before sort2 writes y);
    // `sorted` overwritten in place by sort2 to become `ssrc`.
    u32* sorted   = (u32*)d_ws;                               // E (-> ssrc)
    float* dinv   = (float*)(sorted + E);                     // N
    float* y      = dinv + N;                                 // 2N
    float* gp     = y + 2 * (size_t)N;                        // 2N
    u32* noff     = (u32*)(gp + 2 * (size_t)N);               // N
    u32* cnt      = noff + N;                                 // 512
    u32* offsets  = cnt + MAX_NBUCK;                          // nbuck+1
    u32* part     = (u32*)y;                                  // alias
    float2* out   = (float2*)d_out;

    part_hist_kernel<<<NB, BT, 0, stream>>>(dst, part, E, nbuck);
    colscan_kernel  <<<nbuck, MAX_NB, 0, stream>>>(part, cnt, NB, nbuck);
    offsets_kernel  <<<1, MAX_NBUCK, 0, stream>>>(cnt, offsets, nbuck);
    scatter_kernel  <<<NB, BT, 0, stream>>>(src, dst, part, cnt, offsets,
                                            sorted, E, nbuck, NB);
    sort2_kernel    <<<nbuck, BT, 0, stream>>>(sorted, offsets, x, noff, dinv,
                                               (float2*)y, N);
    agg1_mlp_kernel <<<(8 * N + 255) / 256, 256, 0, stream>>>(sorted, noff,
                                                              (const float2*)y, dinv,
                                                              W1, b1, W2,
                                                              (float2*)gp, N, (u32)E);
    agg2_kernel     <<<(8 * N + 255) / 256, 256, 0, stream>>>(sorted, noff,
                                                              (const float2*)gp, dinv,
                                                              b2, out, N, (u32)E);
}